// Round 10
// baseline (325.909 us; speedup 1.0000x reference)
//
#include <hip/hip_runtime.h>

#define HID 20
#define NLAY 7
#define QHID 5
#define NQ 4

// Pin a value into an AGPR (write) / pull it back (read).
#define AGPR_WRITE(dst, src) asm("v_accvgpr_write_b32 %0, %1" : "=a"(dst) : "v"(src))
#define AGPR_READ(dst, src)  asm("v_accvgpr_read_b32 %0, %1" : "=v"(dst) : "a"(src))

// tanh and its first three derivatives, via one hardware exp.
__device__ __forceinline__ float tanh_derivs(float a, float& d1, float& d2, float& d3) {
    const float e = __expf(2.0f * a);
    const float s = 1.0f - __fdividef(2.0f, e + 1.0f);
    d1 = 1.0f - s * s;               // f'
    d2 = -2.0f * s * d1;             // f''
    d3 = -2.0f * (d1 * d1 + s * d2); // f'''
    return s;
}

#define NCA 8
#define NCB 6

__global__ void __launch_bounds__(256, 1)
pinn_fused(const float* __restrict__ xs, const float* __restrict__ ys, const float* __restrict__ ts,
           const float* __restrict__ W_in, const float* __restrict__ b_in,
           const float* __restrict__ W_hid, const float* __restrict__ b_hid,
           const float* __restrict__ W_out, const float* __restrict__ b_out,
           const float* __restrict__ lam1p, const float* __restrict__ lam2p,
           float* __restrict__ out, int N)
{
    const int idx = blockIdx.x * blockDim.x + threadIdx.x;
    if (idx >= N) return;
    const float xv = xs[idx], yv = ys[idx], tv = ts[idx];
    const float l1 = lam1p[0], l2 = lam2p[0];

    float u, v, p, ux, uy, vx, vy, px, py, lx, ly;

    // ================= Phase A: spatial jet, 8 comps, quarter-split acc =================
    // comps: 0=val 1=gx 2=gy 3=hxx 4=hxy 5=hyy 6=Lx 7=Ly
    {
        float hA_[HID][NCA];          // jet state X (AGPR-pinned, 160)
        float yA_[3 * QHID][NCA];     // stash for quarters 0-2 (AGPR-pinned, 120)

        #pragma unroll
        for (int j = 0; j < HID; ++j) {
            const float w0 = W_in[j], w1 = W_in[HID + j], w2 = W_in[2 * HID + j];
            const float a0 = fmaf(xv, w0, fmaf(yv, w1, fmaf(tv, w2, b_in[j])));
            float d1, d2, d3;
            const float s = tanh_derivs(a0, d1, d2, d3);
            const float g2w = w0 * w0 + w1 * w1;
            float nv[NCA];
            nv[0] = s;
            nv[1] = d1 * w0;
            nv[2] = d1 * w1;
            nv[3] = d2 * w0 * w0;
            nv[4] = d2 * w0 * w1;
            nv[5] = d2 * w1 * w1;
            nv[6] = d3 * w0 * g2w;
            nv[7] = d3 * w1 * g2w;
            #pragma unroll
            for (int c = 0; c < NCA; ++c) AGPR_WRITE(hA_[j][c], nv[c]);
        }

        #pragma unroll 1
        for (int l = 0; l < NLAY; ++l) {
            const float* __restrict__ Wl = W_hid + l * HID * HID;
            const float* __restrict__ bl = b_hid + l * HID;

            #pragma unroll
            for (int q = 0; q < NQ; ++q) {
                float acc[QHID][NCA];  // 40 VGPR hot
                #pragma unroll
                for (int j = 0; j < QHID; ++j) {
                    acc[j][0] = bl[q * QHID + j];
                    #pragma unroll
                    for (int c = 1; c < NCA; ++c) acc[j][c] = 0.0f;
                }
                #pragma unroll
                for (int i = 0; i < HID; ++i) {
                    float r[NCA];
                    #pragma unroll
                    for (int c = 0; c < NCA; ++c) AGPR_READ(r[c], hA_[i][c]);
                    #pragma unroll
                    for (int j = 0; j < QHID; ++j) {
                        const float w = Wl[i * HID + q * QHID + j];
                        #pragma unroll
                        for (int c = 0; c < NCA; ++c) acc[j][c] = fmaf(w, r[c], acc[j][c]);
                    }
                }
                #pragma unroll
                for (int j = 0; j < QHID; ++j) {
                    float d1, d2, d3;
                    const float s = tanh_derivs(acc[j][0], d1, d2, d3);
                    const float gx = acc[j][1], gy = acc[j][2];
                    const float hxx = acc[j][3], hxy = acc[j][4], hyy = acc[j][5];
                    const float g2 = gx * gx + gy * gy;
                    float nv[NCA];
                    nv[0] = s;
                    nv[1] = d1 * gx;
                    nv[2] = d1 * gy;
                    nv[3] = fmaf(d2, gx * gx, d1 * hxx);
                    nv[4] = fmaf(d2, gx * gy, d1 * hxy);
                    nv[5] = fmaf(d2, gy * gy, d1 * hyy);
                    nv[6] = d3 * gx * g2 + d2 * (3.0f * gx * hxx + 2.0f * gy * hxy + gx * hyy) + d1 * acc[j][6];
                    nv[7] = d3 * gy * g2 + d2 * (3.0f * gy * hyy + 2.0f * gx * hxy + gy * hxx) + d1 * acc[j][7];
                    if (q < 3) {
                        #pragma unroll
                        for (int c = 0; c < NCA; ++c) AGPR_WRITE(yA_[q * QHID + j][c], nv[c]);
                    } else {
                        #pragma unroll
                        for (int c = 0; c < NCA; ++c) AGPR_WRITE(hA_[3 * QHID + j][c], nv[c]);
                    }
                }
            }
            // commit stash: X[0..14] = Y
            #pragma unroll
            for (int j = 0; j < 3 * QHID; ++j) {
                #pragma unroll
                for (int c = 0; c < NCA; ++c) {
                    float t;
                    AGPR_READ(t, yA_[j][c]);
                    AGPR_WRITE(hA_[j][c], t);
                }
            }
        }

        float su = 0, sv = 0, sp = 0, sux = 0, suy = 0, svx = 0;
        float spx = 0, spy = 0, slx = 0, sly = 0;
        #pragma unroll
        for (int i = 0; i < HID; ++i) {
            const float w0 = W_out[2 * i], w1 = W_out[2 * i + 1];
            float r[NCA];
            #pragma unroll
            for (int c = 0; c < NCA; ++c) AGPR_READ(r[c], hA_[i][c]);
            sp  = fmaf(w1, r[0], sp);
            sv  = fmaf(w0, r[1], sv);   // psi_x
            su  = fmaf(w0, r[2], su);   // psi_y
            spx = fmaf(w1, r[1], spx);
            spy = fmaf(w1, r[2], spy);
            svx = fmaf(w0, r[3], svx);  // psi_xx
            sux = fmaf(w0, r[4], sux);  // psi_xy
            suy = fmaf(w0, r[5], suy);  // psi_yy
            slx = fmaf(w0, r[6], slx);
            sly = fmaf(w0, r[7], sly);
        }
        u = su; v = -sv; p = sp + b_out[1];
        ux = sux; uy = suy; vx = -svx; vy = -sux;
        px = spx; py = spy; lx = slx; ly = sly;
    }

    // ================= Phase B: time jet, 6 comps, full-width acc =================
    // comps: 0=val 1=gx 2=gy 3=gt 4=hxt 5=hyt
    float ut, vt;
    {
        float hB_[HID][NCB];  // AGPR-pinned (reuses phase-A space)

        #pragma unroll
        for (int j = 0; j < HID; ++j) {
            const float w0 = W_in[j], w1 = W_in[HID + j], w2 = W_in[2 * HID + j];
            const float a0 = fmaf(xv, w0, fmaf(yv, w1, fmaf(tv, w2, b_in[j])));
            float d1, d2, d3;
            const float s = tanh_derivs(a0, d1, d2, d3);
            float nv[NCB];
            nv[0] = s;
            nv[1] = d1 * w0;
            nv[2] = d1 * w1;
            nv[3] = d1 * w2;
            nv[4] = d2 * w0 * w2;
            nv[5] = d2 * w1 * w2;
            #pragma unroll
            for (int c = 0; c < NCB; ++c) AGPR_WRITE(hB_[j][c], nv[c]);
        }

        #pragma unroll 1
        for (int l = 0; l < NLAY; ++l) {
            const float* __restrict__ Wl = W_hid + l * HID * HID;
            const float* __restrict__ bl = b_hid + l * HID;
            float acc[HID][NCB];  // 120 VGPR hot (proven-clean shape)
            #pragma unroll
            for (int j = 0; j < HID; ++j) {
                acc[j][0] = bl[j];
                #pragma unroll
                for (int c = 1; c < NCB; ++c) acc[j][c] = 0.0f;
            }
            #pragma unroll
            for (int i = 0; i < HID; ++i) {
                float r[NCB];
                #pragma unroll
                for (int c = 0; c < NCB; ++c) AGPR_READ(r[c], hB_[i][c]);
                #pragma unroll
                for (int j = 0; j < HID; ++j) {
                    const float w = Wl[i * HID + j];
                    #pragma unroll
                    for (int c = 0; c < NCB; ++c) acc[j][c] = fmaf(w, r[c], acc[j][c]);
                }
            }
            #pragma unroll
            for (int j = 0; j < HID; ++j) {
                float d1, d2, d3;
                const float s = tanh_derivs(acc[j][0], d1, d2, d3);
                const float gx = acc[j][1], gy = acc[j][2], gt = acc[j][3];
                float nv[NCB];
                nv[0] = s;
                nv[1] = d1 * gx;
                nv[2] = d1 * gy;
                nv[3] = d1 * gt;
                nv[4] = fmaf(d2, gx * gt, d1 * acc[j][4]);
                nv[5] = fmaf(d2, gy * gt, d1 * acc[j][5]);
                #pragma unroll
                for (int c = 0; c < NCB; ++c) AGPR_WRITE(hB_[j][c], nv[c]);
            }
        }

        float pxt = 0.0f, pyt = 0.0f;
        #pragma unroll
        for (int i = 0; i < HID; ++i) {
            const float w0 = W_out[2 * i];
            float r4, r5;
            AGPR_READ(r4, hB_[i][4]);
            AGPR_READ(r5, hB_[i][5]);
            pxt = fmaf(w0, r4, pxt);
            pyt = fmaf(w0, r5, pyt);
        }
        ut = pyt;      // psi_yt
        vt = -pxt;     // -psi_xt
    }

    const float fu = ut + l1 * (u * ux + v * uy) + px - l2 * ly;
    const float fv = vt + l1 * (u * vx + v * vy) + py + l2 * lx;

    out[idx]         = u;
    out[N + idx]     = v;
    out[2 * N + idx] = p;
    out[3 * N + idx] = fu;
    out[4 * N + idx] = fv;
}

extern "C" void kernel_launch(void* const* d_in, const int* in_sizes, int n_in,
                              void* d_out, int out_size, void* d_ws, size_t ws_size,
                              hipStream_t stream) {
    const float* xs    = (const float*)d_in[0];
    const float* ys    = (const float*)d_in[1];
    const float* ts    = (const float*)d_in[2];
    const float* W_in  = (const float*)d_in[3];
    const float* b_in  = (const float*)d_in[4];
    const float* W_hid = (const float*)d_in[5];
    const float* b_hid = (const float*)d_in[6];
    const float* W_out = (const float*)d_in[7];
    const float* b_out = (const float*)d_in[8];
    const float* lam1  = (const float*)d_in[9];
    const float* lam2  = (const float*)d_in[10];
    float* out = (float*)d_out;

    const int N = in_sizes[0];
    const int block = 256;
    const int grid = (N + block - 1) / block;
    pinn_fused<<<grid, block, 0, stream>>>(xs, ys, ts, W_in, b_in, W_hid, b_hid,
                                           W_out, b_out, lam1, lam2, out, N);
}

// Round 11
// 184.736 us; speedup vs baseline: 1.7642x; 1.7642x over previous
//
#include <hip/hip_runtime.h>

typedef float  f32x4  __attribute__((ext_vector_type(4)));
typedef short  s16x4  __attribute__((ext_vector_type(4)));
typedef short  bf16x8 __attribute__((ext_vector_type(8)));

#define HID  20
#define NLAY 7
#define NC   11      // 0=val 1=gx 2=gy 3=gt 4=hxx 5=hxy 6=hyy 7=hxt 8=hyt 9=Lx 10=Ly
#define PTS  16      // points per (1-wave) block
#define ST   36      // u16 stride of one (c,pt) row (32 K-pad + 4 bank pad)
#define XIDX(c, p, i) ((((c)*PTS + (p))*ST) + (i))

// tanh and its first three derivatives, via one hardware exp.
__device__ __forceinline__ float tanh_derivs(float a, float& d1, float& d2, float& d3) {
    const float e = __expf(2.0f * a);
    const float s = 1.0f - __fdividef(2.0f, e + 1.0f);
    d1 = 1.0f - s * s;
    d2 = -2.0f * s * d1;
    d3 = -2.0f * (d1 * d1 + s * d2);
    return s;
}

// exact split x = hi + lo (both representable in bf16; products exact in fp32)
__device__ __forceinline__ void bfsplit(float x, unsigned short& h16, unsigned short& l16) {
    const unsigned hb = __float_as_uint(x) & 0xFFFF0000u;
    const float lf = x - __uint_as_float(hb);
    h16 = (unsigned short)(hb >> 16);
    l16 = (unsigned short)(__float_as_uint(lf) >> 16);
}

// ---- setup: pack W_hid (+bias at k=20) into MFMA A-fragments (hi/lo bf16) in ws ----
// A-frag, 16x16x32: lane l holds m = l&15 (j within tile), 8 elements e:
//   e<4: k = 4*(l>>4)+e ; e>=4: k = 16 + 4*(l>>4) + (e-4)   (two stacked K=16 halves)
// ws layout: u32 ws[(((layer*2+jt)*2+hilo)*64 + lane)*4 + r], reg r = elems {2r, 2r+1}
__global__ void wfrag_setup(const float* __restrict__ W_hid,
                            const float* __restrict__ b_hid,
                            unsigned* __restrict__ wsu)
{
    const int l = threadIdx.x;           // 0..63
    const int g = l >> 4, m = l & 15;
    for (int layer = 0; layer < NLAY; ++layer) {
        for (int jt = 0; jt < 2; ++jt) {
            const int j = jt * 16 + m;
            unsigned hi[8], lo[8];
            for (int e = 0; e < 8; ++e) {
                const int k = (e < 4) ? (4 * g + e) : (16 + 4 * g + (e - 4));
                float w = 0.0f;
                if (j < HID) {
                    if (k < HID)       w = W_hid[(layer * HID + k) * HID + j];
                    else if (k == HID) w = b_hid[layer * HID + j];
                }
                const unsigned hb = __float_as_uint(w) & 0xFFFF0000u;
                const float lf = w - __uint_as_float(hb);
                hi[e] = hb >> 16;
                lo[e] = __float_as_uint(lf) >> 16;
            }
            unsigned* ph = wsu + (((layer * 2 + jt) * 2 + 0) * 64 + l) * 4;
            unsigned* pl = wsu + (((layer * 2 + jt) * 2 + 1) * 64 + l) * 4;
            for (int r = 0; r < 4; ++r) {
                ph[r] = hi[2 * r] | (hi[2 * r + 1] << 16);
                pl[r] = lo[2 * r] | (lo[2 * r + 1] << 16);
            }
        }
    }
}

__global__ void __launch_bounds__(64)
pinn_mfma(const float* __restrict__ xs, const float* __restrict__ ys, const float* __restrict__ ts,
          const float* __restrict__ W_in, const float* __restrict__ b_in,
          const float* __restrict__ W_out, const float* __restrict__ b_out,
          const float* __restrict__ lam1p, const float* __restrict__ lam2p,
          const unsigned* __restrict__ wsu,
          float* __restrict__ out, int N)
{
    __shared__ __align__(16) unsigned short XH[NC * PTS * ST];
    __shared__ __align__(16) unsigned short XL[NC * PTS * ST];

    const int l  = threadIdx.x;
    const int g  = l >> 4, pt = l & 15;
    const int idx0 = blockIdx.x * PTS;
    const int pi = min(idx0 + pt, N - 1);   // clamped point index (tail-safe)

    // ---- init K-pad rows i=20..31: comp0 i=20 is the bias-one, everything else 0 ----
    for (int z = l; z < NC * PTS * 12; z += 64) {
        const int c  = z / (PTS * 12);
        const int rm = z % (PTS * 12);
        const int pp = rm / 12;
        const int ii = 20 + rm % 12;
        XH[XIDX(c, pp, ii)] = (c == 0 && ii == 20) ? (unsigned short)0x3F80 : (unsigned short)0;
        XL[XIDX(c, pp, ii)] = 0;
    }

    // ---- input layer: lane handles neurons j = 5g..5g+4 of its point ----
    const float xv = xs[pi], yv = ys[pi], tv = ts[pi];
    #pragma unroll
    for (int n = 0; n < 5; ++n) {
        const int j = 5 * g + n;
        const float w0 = W_in[j], w1 = W_in[HID + j], w2 = W_in[2 * HID + j];
        const float a0 = fmaf(xv, w0, fmaf(yv, w1, fmaf(tv, w2, b_in[j])));
        float d1, d2, d3;
        const float s = tanh_derivs(a0, d1, d2, d3);
        const float g2w = w0 * w0 + w1 * w1;
        float nv[NC];
        nv[0] = s;        nv[1] = d1 * w0;  nv[2] = d1 * w1;  nv[3] = d1 * w2;
        nv[4] = d2 * w0 * w0; nv[5] = d2 * w0 * w1; nv[6] = d2 * w1 * w1;
        nv[7] = d2 * w0 * w2; nv[8] = d2 * w1 * w2;
        nv[9] = d3 * w0 * g2w; nv[10] = d3 * w1 * g2w;
        #pragma unroll
        for (int c = 0; c < NC; ++c) {
            unsigned short h16, l16; bfsplit(nv[c], h16, l16);
            XH[XIDX(c, pt, j)] = h16;
            XL[XIDX(c, pt, j)] = l16;
        }
    }
    asm volatile("s_waitcnt lgkmcnt(0)" ::: "memory");
    __builtin_amdgcn_sched_barrier(0);

    // ---- hidden layers: MFMA matmul (all 11 comps), in-lane activation ----
    #pragma unroll 1
    for (int layer = 0; layer < NLAY; ++layer) {
        const bf16x8 ah0 = *(const bf16x8*)(wsu + (((layer * 2 + 0) * 2 + 0) * 64 + l) * 4);
        const bf16x8 al0 = *(const bf16x8*)(wsu + (((layer * 2 + 0) * 2 + 1) * 64 + l) * 4);
        const bf16x8 ah1 = *(const bf16x8*)(wsu + (((layer * 2 + 1) * 2 + 0) * 64 + l) * 4);
        const bf16x8 al1 = *(const bf16x8*)(wsu + (((layer * 2 + 1) * 2 + 1) * 64 + l) * 4);

        f32x4 acc[NC][2];
        #pragma unroll
        for (int c = 0; c < NC; ++c) {
            acc[c][0] = (f32x4){0.f, 0.f, 0.f, 0.f};
            acc[c][1] = (f32x4){0.f, 0.f, 0.f, 0.f};
        }

        #pragma unroll
        for (int c = 0; c < NC; ++c) {
            const int rb = XIDX(c, pt, 4 * g);
            const s16x4 xha = *(const s16x4*)&XH[rb];
            const s16x4 xhb = *(const s16x4*)&XH[rb + 16];
            const s16x4 xla = *(const s16x4*)&XL[rb];
            const s16x4 xlb = *(const s16x4*)&XL[rb + 16];
            const bf16x8 Bh = __builtin_shufflevector(xha, xhb, 0, 1, 2, 3, 4, 5, 6, 7);
            const bf16x8 Bl = __builtin_shufflevector(xla, xlb, 0, 1, 2, 3, 4, 5, 6, 7);
            acc[c][0] = __builtin_amdgcn_mfma_f32_16x16x32_bf16(ah0, Bh, acc[c][0], 0, 0, 0);
            acc[c][0] = __builtin_amdgcn_mfma_f32_16x16x32_bf16(ah0, Bl, acc[c][0], 0, 0, 0);
            acc[c][0] = __builtin_amdgcn_mfma_f32_16x16x32_bf16(al0, Bh, acc[c][0], 0, 0, 0);
            acc[c][0] = __builtin_amdgcn_mfma_f32_16x16x32_bf16(al0, Bl, acc[c][0], 0, 0, 0);
            acc[c][1] = __builtin_amdgcn_mfma_f32_16x16x32_bf16(ah1, Bh, acc[c][1], 0, 0, 0);
            acc[c][1] = __builtin_amdgcn_mfma_f32_16x16x32_bf16(ah1, Bl, acc[c][1], 0, 0, 0);
            acc[c][1] = __builtin_amdgcn_mfma_f32_16x16x32_bf16(al1, Bh, acc[c][1], 0, 0, 0);
            acc[c][1] = __builtin_amdgcn_mfma_f32_16x16x32_bf16(al1, Bl, acc[c][1], 0, 0, 0);
        }
        asm volatile("s_waitcnt lgkmcnt(0)" ::: "memory");
        __builtin_amdgcn_sched_barrier(0);

        // activation: C/D layout → lane holds j = jt*16 + 4g + q at acc[c][jt][q]
        #pragma unroll
        for (int q = 0; q < 4; ++q) {
            const int j = 4 * g + q;
            float a[NC];
            #pragma unroll
            for (int c = 0; c < NC; ++c) a[c] = acc[c][0][q];
            float d1, d2, d3;
            const float s = tanh_derivs(a[0], d1, d2, d3);
            const float gx = a[1], gy = a[2], gt = a[3];
            const float hxx = a[4], hxy = a[5], hyy = a[6];
            const float hxt = a[7], hyt = a[8];
            const float g2 = gx * gx + gy * gy;
            float nv[NC];
            nv[0] = s;
            nv[1] = d1 * gx;  nv[2] = d1 * gy;  nv[3] = d1 * gt;
            nv[4] = fmaf(d2, gx * gx, d1 * hxx);
            nv[5] = fmaf(d2, gx * gy, d1 * hxy);
            nv[6] = fmaf(d2, gy * gy, d1 * hyy);
            nv[7] = fmaf(d2, gx * gt, d1 * hxt);
            nv[8] = fmaf(d2, gy * gt, d1 * hyt);
            nv[9]  = d3 * gx * g2 + d2 * (3.f * gx * hxx + 2.f * gy * hxy + gx * hyy) + d1 * a[9];
            nv[10] = d3 * gy * g2 + d2 * (3.f * gy * hyy + 2.f * gx * hxy + gy * hxx) + d1 * a[10];
            #pragma unroll
            for (int c = 0; c < NC; ++c) {
                unsigned short h16, l16; bfsplit(nv[c], h16, l16);
                XH[XIDX(c, pt, j)] = h16;
                XL[XIDX(c, pt, j)] = l16;
            }
        }
        if (g == 0) {   // tile 2 holds real neurons 16..19 only in lane-group 0
            #pragma unroll
            for (int q = 0; q < 4; ++q) {
                const int j = 16 + q;
                float a[NC];
                #pragma unroll
                for (int c = 0; c < NC; ++c) a[c] = acc[c][1][q];
                float d1, d2, d3;
                const float s = tanh_derivs(a[0], d1, d2, d3);
                const float gx = a[1], gy = a[2], gt = a[3];
                const float hxx = a[4], hxy = a[5], hyy = a[6];
                const float hxt = a[7], hyt = a[8];
                const float g2 = gx * gx + gy * gy;
                float nv[NC];
                nv[0] = s;
                nv[1] = d1 * gx;  nv[2] = d1 * gy;  nv[3] = d1 * gt;
                nv[4] = fmaf(d2, gx * gx, d1 * hxx);
                nv[5] = fmaf(d2, gx * gy, d1 * hxy);
                nv[6] = fmaf(d2, gy * gy, d1 * hyy);
                nv[7] = fmaf(d2, gx * gt, d1 * hxt);
                nv[8] = fmaf(d2, gy * gt, d1 * hyt);
                nv[9]  = d3 * gx * g2 + d2 * (3.f * gx * hxx + 2.f * gy * hxy + gx * hyy) + d1 * a[9];
                nv[10] = d3 * gy * g2 + d2 * (3.f * gy * hyy + 2.f * gx * hxy + gy * hxx) + d1 * a[10];
                #pragma unroll
                for (int c = 0; c < NC; ++c) {
                    unsigned short h16, l16; bfsplit(nv[c], h16, l16);
                    XH[XIDX(c, pt, j)] = h16;
                    XL[XIDX(c, pt, j)] = l16;
                }
            }
        }
        asm volatile("s_waitcnt lgkmcnt(0)" ::: "memory");
        __builtin_amdgcn_sched_barrier(0);
    }

    // ---- output layer (16 lanes, one per point) ----
    if (g == 0 && idx0 + pt < N) {
        const float l1 = lam1p[0], l2 = lam2p[0];
        float su = 0, sv = 0, sp = 0, sux = 0, suy = 0, svx = 0;
        float spx = 0, spy = 0, sut = 0, svt = 0, slx = 0, sly = 0;
        #pragma unroll
        for (int i = 0; i < HID; ++i) {
            const float w0 = W_out[2 * i], w1 = W_out[2 * i + 1];
            float r[NC];
            #pragma unroll
            for (int c = 0; c < NC; ++c) {
                if (c == 3) { r[c] = 0.0f; continue; }   // gt unused by outputs
                const unsigned hh = XH[XIDX(c, pt, i)];
                const unsigned ll = XL[XIDX(c, pt, i)];
                r[c] = __uint_as_float(hh << 16) + __uint_as_float(ll << 16);
            }
            sp  = fmaf(w1, r[0], sp);
            sv  = fmaf(w0, r[1], sv);    // psi_x
            su  = fmaf(w0, r[2], su);    // psi_y
            spx = fmaf(w1, r[1], spx);
            spy = fmaf(w1, r[2], spy);
            svx = fmaf(w0, r[4], svx);   // psi_xx
            sux = fmaf(w0, r[5], sux);   // psi_xy
            suy = fmaf(w0, r[6], suy);   // psi_yy
            svt = fmaf(w0, r[7], svt);   // psi_xt
            sut = fmaf(w0, r[8], sut);   // psi_yt
            slx = fmaf(w0, r[9], slx);
            sly = fmaf(w0, r[10], sly);
        }
        const float u = su, v = -sv, p = sp + b_out[1];
        const float fu = sut + l1 * (u * sux + v * suy) + spx - l2 * sly;
        const float fv = -svt + l1 * (u * (-svx) + v * (-sux)) + spy + l2 * slx;
        out[idx0 + pt]         = u;
        out[N + idx0 + pt]     = v;
        out[2 * N + idx0 + pt] = p;
        out[3 * N + idx0 + pt] = fu;
        out[4 * N + idx0 + pt] = fv;
    }
}

extern "C" void kernel_launch(void* const* d_in, const int* in_sizes, int n_in,
                              void* d_out, int out_size, void* d_ws, size_t ws_size,
                              hipStream_t stream) {
    const float* xs    = (const float*)d_in[0];
    const float* ys    = (const float*)d_in[1];
    const float* ts    = (const float*)d_in[2];
    const float* W_in  = (const float*)d_in[3];
    const float* b_in  = (const float*)d_in[4];
    const float* W_hid = (const float*)d_in[5];
    const float* b_hid = (const float*)d_in[6];
    const float* W_out = (const float*)d_in[7];
    const float* b_out = (const float*)d_in[8];
    const float* lam1  = (const float*)d_in[9];
    const float* lam2  = (const float*)d_in[10];
    float* out = (float*)d_out;

    const int N = in_sizes[0];
    wfrag_setup<<<1, 64, 0, stream>>>(W_hid, b_hid, (unsigned*)d_ws);
    const int grid = (N + PTS - 1) / PTS;
    pinn_mfma<<<grid, 64, 0, stream>>>(xs, ys, ts, W_in, b_in, W_out, b_out,
                                       lam1, lam2, (const unsigned*)d_ws, out, N);
}

// Round 13
// 136.373 us; speedup vs baseline: 2.3898x; 1.3546x over previous
//
#include <hip/hip_runtime.h>

typedef float  f32x4  __attribute__((ext_vector_type(4)));
typedef short  bf16x8 __attribute__((ext_vector_type(8)));
typedef unsigned int u32;
typedef u32 u32x4 __attribute__((ext_vector_type(4)));

#define HID  20
#define NLAY 7
#define NC   11      // 0=val 1=gx 2=gy 3=gt 4=hxx 5=hxy 6=hyy 7=hxt 8=hyt 9=Lx 10=Ly
#define PTS  16

__device__ __forceinline__ float tanh_derivs(float a, float& d1, float& d2, float& d3) {
    const float e = __expf(2.0f * a);
    const float s = 1.0f - __fdividef(2.0f, e + 1.0f);
    d1 = 1.0f - s * s;
    d2 = -2.0f * s * d1;
    d3 = -2.0f * (d1 * d1 + s * d2);
    return s;
}

// jet chain rule through tanh: a[] = pre-activation jet, nv[] = post-activation jet
__device__ __forceinline__ void jet_activate(const float* a, float* nv) {
    float d1, d2, d3;
    const float s = tanh_derivs(a[0], d1, d2, d3);
    const float gx = a[1], gy = a[2], gt = a[3];
    const float hxx = a[4], hxy = a[5], hyy = a[6];
    const float hxt = a[7], hyt = a[8];
    const float g2 = gx * gx + gy * gy;
    nv[0] = s;
    nv[1] = d1 * gx;  nv[2] = d1 * gy;  nv[3] = d1 * gt;
    nv[4] = fmaf(d2, gx * gx, d1 * hxx);
    nv[5] = fmaf(d2, gx * gy, d1 * hxy);
    nv[6] = fmaf(d2, gy * gy, d1 * hyy);
    nv[7] = fmaf(d2, gx * gt, d1 * hxt);
    nv[8] = fmaf(d2, gy * gt, d1 * hyt);
    nv[9]  = d3 * gx * g2 + d2 * (3.f * gx * hxx + 2.f * gy * hxy + gx * hyy) + d1 * a[9];
    nv[10] = d3 * gy * g2 + d2 * (3.f * gy * hyy + 2.f * gx * hxy + gy * hxx) + d1 * a[10];
}

// pack pair (v0 -> low half, v1 -> high half): truncated-bf16 hi word + residual-bf16 lo word
__device__ __forceinline__ void pack_pair(float v0, float v1, u32& wh, u32& wl) {
    const u32 b0 = __float_as_uint(v0);
    const u32 b1 = __float_as_uint(v1);
    wh = (b0 >> 16) | (b1 & 0xFFFF0000u);
    const float l0 = v0 - __uint_as_float(b0 & 0xFFFF0000u);
    const float l1 = v1 - __uint_as_float(b1 & 0xFFFF0000u);
    wl = (__float_as_uint(l0) >> 16) | (__float_as_uint(l1) & 0xFFFF0000u);
}

__device__ __forceinline__ void input_neuron(int j, float xv, float yv, float tv,
                                             const float* __restrict__ W_in,
                                             const float* __restrict__ b_in, float* nv) {
    const float w0 = W_in[j], w1 = W_in[HID + j], w2 = W_in[2 * HID + j];
    const float a0 = fmaf(xv, w0, fmaf(yv, w1, fmaf(tv, w2, b_in[j])));
    float d1, d2, d3;
    const float s = tanh_derivs(a0, d1, d2, d3);
    const float g2w = w0 * w0 + w1 * w1;
    nv[0] = s;        nv[1] = d1 * w0;  nv[2] = d1 * w1;  nv[3] = d1 * w2;
    nv[4] = d2 * w0 * w0; nv[5] = d2 * w0 * w1; nv[6] = d2 * w1 * w1;
    nv[7] = d2 * w0 * w2; nv[8] = d2 * w1 * w2;
    nv[9] = d3 * w0 * g2w; nv[10] = d3 * w1 * g2w;
}

// ---- setup: pack W_hid (+bias at k=20) into MFMA A-fragments (hi/lo bf16) in ws ----
// identical to round-11 (HW-verified): lane l holds m=l&15, e<4: k=4*(l>>4)+e ; e>=4: k=16+4*(l>>4)+(e-4)
__global__ void wfrag_setup(const float* __restrict__ W_hid,
                            const float* __restrict__ b_hid,
                            unsigned* __restrict__ wsu)
{
    const int l = threadIdx.x;
    const int g = l >> 4, m = l & 15;
    for (int layer = 0; layer < NLAY; ++layer) {
        for (int jt = 0; jt < 2; ++jt) {
            const int j = jt * 16 + m;
            unsigned hi[8], lo[8];
            for (int e = 0; e < 8; ++e) {
                const int k = (e < 4) ? (4 * g + e) : (16 + 4 * g + (e - 4));
                float w = 0.0f;
                if (j < HID) {
                    if (k < HID)       w = W_hid[(layer * HID + k) * HID + j];
                    else if (k == HID) w = b_hid[layer * HID + j];
                }
                const unsigned hb = __float_as_uint(w) & 0xFFFF0000u;
                const float lf = w - __uint_as_float(hb);
                hi[e] = hb >> 16;
                lo[e] = __float_as_uint(lf) >> 16;
            }
            unsigned* ph = wsu + (((layer * 2 + jt) * 2 + 0) * 64 + l) * 4;
            unsigned* pl = wsu + (((layer * 2 + jt) * 2 + 1) * 64 + l) * 4;
            for (int r = 0; r < 4; ++r) {
                ph[r] = hi[2 * r] | (hi[2 * r + 1] << 16);
                pl[r] = lo[2 * r] | (lo[2 * r + 1] << 16);
            }
        }
    }
}

__global__ void __launch_bounds__(64)
pinn_mfma_reg(const float* __restrict__ xs, const float* __restrict__ ys, const float* __restrict__ ts,
              const float* __restrict__ W_in, const float* __restrict__ b_in,
              const float* __restrict__ W_out, const float* __restrict__ b_out,
              const float* __restrict__ lam1p, const float* __restrict__ lam2p,
              const unsigned* __restrict__ wsu,
              float* __restrict__ out, int N)
{
    const int l  = threadIdx.x;
    const int g  = l >> 4, pt = l & 15;
    const int idx0 = blockIdx.x * PTS;
    const int pi = min(idx0 + pt, N - 1);

    // Layer-input B-fragments, fully register-resident: per comp, 8 bf16 (4 u32) hi + lo.
    // element e=q <-> k=4g+q (tile1 j's), e=4+q <-> k=16+4g+q (tile2 j's / bias / pad)
    u32x4 Bh[NC], Bl[NC];

    // ---- input layer ----
    const float xv = xs[pi], yv = ys[pi], tv = ts[pi];
    #pragma unroll
    for (int pr = 0; pr < 2; ++pr) {
        float nvA[NC], nvB[NC];
        input_neuron(4 * g + 2 * pr,     xv, yv, tv, W_in, b_in, nvA);
        input_neuron(4 * g + 2 * pr + 1, xv, yv, tv, W_in, b_in, nvB);
        #pragma unroll
        for (int c = 0; c < NC; ++c) {
            u32 th, tl;
            pack_pair(nvA[c], nvB[c], th, tl);
            Bh[c][pr] = th; Bl[c][pr] = tl;
        }
    }
    if (g == 0) {
        #pragma unroll
        for (int pr = 0; pr < 2; ++pr) {
            float nvA[NC], nvB[NC];
            input_neuron(16 + 2 * pr,     xv, yv, tv, W_in, b_in, nvA);
            input_neuron(16 + 2 * pr + 1, xv, yv, tv, W_in, b_in, nvB);
            #pragma unroll
            for (int c = 0; c < NC; ++c) {
                u32 th, tl;
                pack_pair(nvA[c], nvB[c], th, tl);
                Bh[c][2 + pr] = th; Bl[c][2 + pr] = tl;
            }
        }
    } else {
        #pragma unroll
        for (int c = 0; c < NC; ++c) { Bh[c][2] = 0u; Bh[c][3] = 0u; Bl[c][2] = 0u; Bl[c][3] = 0u; }
    }
    // bias row k=20 (g==1, e=4): X=1.0 in comp 0 only
    Bh[0][2] = (g == 1) ? 0x3F80u : Bh[0][2];
    Bl[0][2] = (g == 1) ? 0u      : Bl[0][2];

    // ---- hidden layers: all-register MFMA chain ----
    const u32x4* wp = (const u32x4*)wsu;
    u32x4 f0 = wp[((0 * 2 + 0) * 2 + 0) * 64 + l];
    u32x4 f1 = wp[((0 * 2 + 0) * 2 + 1) * 64 + l];
    u32x4 f2 = wp[((0 * 2 + 1) * 2 + 0) * 64 + l];
    u32x4 f3 = wp[((0 * 2 + 1) * 2 + 1) * 64 + l];

    #pragma unroll 1
    for (int layer = 0; layer < NLAY; ++layer) {
        const int nl = (layer + 1 < NLAY) ? layer + 1 : layer;  // prefetch next layer's frags
        u32x4 n0 = wp[((nl * 2 + 0) * 2 + 0) * 64 + l];
        u32x4 n1 = wp[((nl * 2 + 0) * 2 + 1) * 64 + l];
        u32x4 n2 = wp[((nl * 2 + 1) * 2 + 0) * 64 + l];
        u32x4 n3 = wp[((nl * 2 + 1) * 2 + 1) * 64 + l];

        const bf16x8 ah0 = __builtin_bit_cast(bf16x8, f0);
        const bf16x8 al0 = __builtin_bit_cast(bf16x8, f1);
        const bf16x8 ah1 = __builtin_bit_cast(bf16x8, f2);
        const bf16x8 al1 = __builtin_bit_cast(bf16x8, f3);

        f32x4 acc1[NC], acc2[NC];
        #pragma unroll
        for (int c = 0; c < NC; ++c) {
            const bf16x8 bh = __builtin_bit_cast(bf16x8, Bh[c]);
            const bf16x8 bl = __builtin_bit_cast(bf16x8, Bl[c]);
            const f32x4 z = (f32x4){0.f, 0.f, 0.f, 0.f};
            f32x4 a1 = __builtin_amdgcn_mfma_f32_16x16x32_bf16(ah0, bh, z, 0, 0, 0);
            a1 = __builtin_amdgcn_mfma_f32_16x16x32_bf16(ah0, bl, a1, 0, 0, 0);
            a1 = __builtin_amdgcn_mfma_f32_16x16x32_bf16(al0, bh, a1, 0, 0, 0);
            acc1[c] = a1;
            f32x4 a2 = __builtin_amdgcn_mfma_f32_16x16x32_bf16(ah1, bh, z, 0, 0, 0);
            a2 = __builtin_amdgcn_mfma_f32_16x16x32_bf16(ah1, bl, a2, 0, 0, 0);
            a2 = __builtin_amdgcn_mfma_f32_16x16x32_bf16(al1, bh, a2, 0, 0, 0);
            acc2[c] = a2;
        }

        // activation + repack into next B (uniform across lanes: g>0 tile2 accs are exactly 0)
        #pragma unroll
        for (int pr = 0; pr < 2; ++pr) {
            float aA[NC], aB[NC], nvA[NC], nvB[NC];
            #pragma unroll
            for (int c = 0; c < NC; ++c) { aA[c] = acc1[c][2 * pr]; aB[c] = acc1[c][2 * pr + 1]; }
            jet_activate(aA, nvA);
            jet_activate(aB, nvB);
            #pragma unroll
            for (int c = 0; c < NC; ++c) {
                u32 th, tl;
                pack_pair(nvA[c], nvB[c], th, tl);
                Bh[c][pr] = th; Bl[c][pr] = tl;
            }
        }
        #pragma unroll
        for (int pr = 0; pr < 2; ++pr) {
            float aA[NC], aB[NC], nvA[NC], nvB[NC];
            #pragma unroll
            for (int c = 0; c < NC; ++c) { aA[c] = acc2[c][2 * pr]; aB[c] = acc2[c][2 * pr + 1]; }
            jet_activate(aA, nvA);
            jet_activate(aB, nvB);
            #pragma unroll
            for (int c = 0; c < NC; ++c) {
                u32 th, tl;
                pack_pair(nvA[c], nvB[c], th, tl);
                Bh[c][2 + pr] = th; Bl[c][2 + pr] = tl;
            }
        }
        Bh[0][2] = (g == 1) ? 0x3F80u : Bh[0][2];
        Bl[0][2] = (g == 1) ? 0u      : Bl[0][2];

        f0 = n0; f1 = n1; f2 = n2; f3 = n3;
    }

    // ---- output layer: per-lane partials over its j's, then cross-group shuffle reduce ----
    float su = 0, sv = 0, sp = 0, spx = 0, spy = 0, svx = 0;
    float sux = 0, suy = 0, svt = 0, sut = 0, slx = 0, sly = 0;

    #pragma unroll
    for (int q = 0; q < 4; ++q) {
        // tile1: j = 4g+q (always a real neuron)
        {
            const int j = 4 * g + q;
            const float w0 = W_out[2 * j], w1 = W_out[2 * j + 1];
            float r[NC];
            #pragma unroll
            for (int c = 0; c < NC; ++c) {
                if (c == 3) { r[c] = 0.0f; continue; }  // gt unused by outputs
                const u32 wh = Bh[c][q >> 1], wl = Bl[c][q >> 1];
                const u32 hh = (q & 1) ? (wh & 0xFFFF0000u) : (wh << 16);
                const u32 ll = (q & 1) ? (wl & 0xFFFF0000u) : (wl << 16);
                r[c] = __uint_as_float(hh) + __uint_as_float(ll);
            }
            sp  = fmaf(w1, r[0], sp);
            sv  = fmaf(w0, r[1], sv);    spx = fmaf(w1, r[1], spx);
            su  = fmaf(w0, r[2], su);    spy = fmaf(w1, r[2], spy);
            svx = fmaf(w0, r[4], svx);
            sux = fmaf(w0, r[5], sux);
            suy = fmaf(w0, r[6], suy);
            svt = fmaf(w0, r[7], svt);
            sut = fmaf(w0, r[8], sut);
            slx = fmaf(w0, r[9], slx);
            sly = fmaf(w0, r[10], sly);
        }
        // tile2: j2 = 16+4g+q (real only when < 20; bias/pad masked out)
        {
            const int j2 = 16 + 4 * g + q;
            const int jc = (j2 < HID) ? j2 : 0;
            const float valid = (j2 < HID) ? 1.0f : 0.0f;
            const float w0 = W_out[2 * jc] * valid, w1 = W_out[2 * jc + 1] * valid;
            float r[NC];
            #pragma unroll
            for (int c = 0; c < NC; ++c) {
                if (c == 3) { r[c] = 0.0f; continue; }
                const u32 wh = Bh[c][2 + (q >> 1)], wl = Bl[c][2 + (q >> 1)];
                const u32 hh = (q & 1) ? (wh & 0xFFFF0000u) : (wh << 16);
                const u32 ll = (q & 1) ? (wl & 0xFFFF0000u) : (wl << 16);
                r[c] = __uint_as_float(hh) + __uint_as_float(ll);
            }
            sp  = fmaf(w1, r[0], sp);
            sv  = fmaf(w0, r[1], sv);    spx = fmaf(w1, r[1], spx);
            su  = fmaf(w0, r[2], su);    spy = fmaf(w1, r[2], spy);
            svx = fmaf(w0, r[4], svx);
            sux = fmaf(w0, r[5], sux);
            suy = fmaf(w0, r[6], suy);
            svt = fmaf(w0, r[7], svt);
            sut = fmaf(w0, r[8], sut);
            slx = fmaf(w0, r[9], slx);
            sly = fmaf(w0, r[10], sly);
        }
    }

    // reduce over the 4 lane-groups (lanes l, l^16, l^32, l^48 share pt)
    #define RED_(x) x += __shfl_xor(x, 16); x += __shfl_xor(x, 32)
    RED_(su); RED_(sv); RED_(sp); RED_(spx); RED_(spy); RED_(svx);
    RED_(sux); RED_(suy); RED_(svt); RED_(sut); RED_(slx); RED_(sly);
    #undef RED_

    if (g == 0 && idx0 + pt < N) {
        const float l1 = lam1p[0], l2 = lam2p[0];
        const float u = su, v = -sv, p = sp + b_out[1];
        const float fu = sut + l1 * (u * sux + v * suy) + spx - l2 * sly;
        const float fv = -svt + l1 * (u * (-svx) + v * (-sux)) + spy + l2 * slx;
        out[idx0 + pt]         = u;
        out[N + idx0 + pt]     = v;
        out[2 * N + idx0 + pt] = p;
        out[3 * N + idx0 + pt] = fu;
        out[4 * N + idx0 + pt] = fv;
    }
}

extern "C" void kernel_launch(void* const* d_in, const int* in_sizes, int n_in,
                              void* d_out, int out_size, void* d_ws, size_t ws_size,
                              hipStream_t stream) {
    const float* xs    = (const float*)d_in[0];
    const float* ys    = (const float*)d_in[1];
    const float* ts    = (const float*)d_in[2];
    const float* W_in  = (const float*)d_in[3];
    const float* b_in  = (const float*)d_in[4];
    const float* W_hid = (const float*)d_in[5];
    const float* b_hid = (const float*)d_in[6];
    const float* W_out = (const float*)d_in[7];
    const float* b_out = (const float*)d_in[8];
    const float* lam1  = (const float*)d_in[9];
    const float* lam2  = (const float*)d_in[10];
    float* out = (float*)d_out;

    const int N = in_sizes[0];
    wfrag_setup<<<1, 64, 0, stream>>>(W_hid, b_hid, (unsigned*)d_ws);
    const int grid = (N + PTS - 1) / PTS;
    pinn_mfma_reg<<<grid, 64, 0, stream>>>(xs, ys, ts, W_in, b_in, W_out, b_out,
                                           lam1, lam2, (const unsigned*)d_ws, out, N);
}

// Round 14
// 124.970 us; speedup vs baseline: 2.6079x; 1.0912x over previous
//
#include <hip/hip_runtime.h>

typedef float  f32x4  __attribute__((ext_vector_type(4)));
typedef short  bf16x8 __attribute__((ext_vector_type(8)));
typedef unsigned int u32;
typedef u32 u32x4 __attribute__((ext_vector_type(4)));

#define HID  20
#define NLAY 7
#define NC   11      // 0=val 1=gx 2=gy 3=gt 4=hxx 5=hxy 6=hyy 7=hxt 8=hyt 9=Lx 10=Ly
#define PTS  16

__device__ __forceinline__ float tanh_derivs(float a, float& d1, float& d2, float& d3) {
    const float e = __expf(2.0f * a);
    const float s = 1.0f - __fdividef(2.0f, e + 1.0f);
    d1 = 1.0f - s * s;
    d2 = -2.0f * s * d1;
    d3 = -2.0f * (d1 * d1 + s * d2);
    return s;
}

// jet chain rule through tanh: a[] = pre-activation jet, nv[] = post-activation jet
__device__ __forceinline__ void jet_activate(const float* a, float* nv) {
    float d1, d2, d3;
    const float s = tanh_derivs(a[0], d1, d2, d3);
    const float gx = a[1], gy = a[2], gt = a[3];
    const float hxx = a[4], hxy = a[5], hyy = a[6];
    const float hxt = a[7], hyt = a[8];
    const float g2 = gx * gx + gy * gy;
    nv[0] = s;
    nv[1] = d1 * gx;  nv[2] = d1 * gy;  nv[3] = d1 * gt;
    nv[4] = fmaf(d2, gx * gx, d1 * hxx);
    nv[5] = fmaf(d2, gx * gy, d1 * hxy);
    nv[6] = fmaf(d2, gy * gy, d1 * hyy);
    nv[7] = fmaf(d2, gx * gt, d1 * hxt);
    nv[8] = fmaf(d2, gy * gt, d1 * hyt);
    nv[9]  = d3 * gx * g2 + d2 * (3.f * gx * hxx + 2.f * gy * hxy + gx * hyy) + d1 * a[9];
    nv[10] = d3 * gy * g2 + d2 * (3.f * gy * hyy + 2.f * gx * hxy + gy * hxx) + d1 * a[10];
}

// packed bf16 convert: dst.lo16 = bf16(a), dst.hi16 = bf16(b)  (RNE)
__device__ __forceinline__ u32 cvt_pk_bf16(float a, float b) {
    u32 r;
    asm("v_cvt_pk_bf16_f32 %0, %1, %2" : "=v"(r) : "v"(a), "v"(b));
    return r;
}

// hi word + exact residual lo word
__device__ __forceinline__ void pack_pair(float v0, float v1, u32& wh, u32& wl) {
    wh = cvt_pk_bf16(v0, v1);
    const float h0 = __uint_as_float(wh << 16);
    const float h1 = __uint_as_float(wh & 0xFFFF0000u);
    wl = cvt_pk_bf16(v0 - h0, v1 - h1);
}

__device__ __forceinline__ void input_neuron(int j, float xv, float yv, float tv,
                                             const float* __restrict__ W_in,
                                             const float* __restrict__ b_in, float* nv) {
    const float w0 = W_in[j], w1 = W_in[HID + j], w2 = W_in[2 * HID + j];
    const float a0 = fmaf(xv, w0, fmaf(yv, w1, fmaf(tv, w2, b_in[j])));
    float d1, d2, d3;
    const float s = tanh_derivs(a0, d1, d2, d3);
    const float g2w = w0 * w0 + w1 * w1;
    nv[0] = s;        nv[1] = d1 * w0;  nv[2] = d1 * w1;  nv[3] = d1 * w2;
    nv[4] = d2 * w0 * w0; nv[5] = d2 * w0 * w1; nv[6] = d2 * w1 * w1;
    nv[7] = d2 * w0 * w2; nv[8] = d2 * w1 * w2;
    nv[9] = d3 * w0 * g2w; nv[10] = d3 * w1 * g2w;
}

// ---- setup: pack W_hid (+bias at k=20) into MFMA A-fragments (hi/lo bf16) in ws ----
// HW-verified (r11/r13): lane l holds m=l&15, e<4: k=4*(l>>4)+e ; e>=4: k=16+4*(l>>4)+(e-4)
__global__ void wfrag_setup(const float* __restrict__ W_hid,
                            const float* __restrict__ b_hid,
                            unsigned* __restrict__ wsu)
{
    const int l = threadIdx.x;
    const int g = l >> 4, m = l & 15;
    for (int layer = 0; layer < NLAY; ++layer) {
        for (int jt = 0; jt < 2; ++jt) {
            const int j = jt * 16 + m;
            unsigned hi[8], lo[8];
            for (int e = 0; e < 8; ++e) {
                const int k = (e < 4) ? (4 * g + e) : (16 + 4 * g + (e - 4));
                float w = 0.0f;
                if (j < HID) {
                    if (k < HID)       w = W_hid[(layer * HID + k) * HID + j];
                    else if (k == HID) w = b_hid[layer * HID + j];
                }
                const unsigned hb = __float_as_uint(w) & 0xFFFF0000u;
                const float lf = w - __uint_as_float(hb);
                hi[e] = hb >> 16;
                lo[e] = __float_as_uint(lf) >> 16;
            }
            unsigned* ph = wsu + (((layer * 2 + jt) * 2 + 0) * 64 + l) * 4;
            unsigned* pl = wsu + (((layer * 2 + jt) * 2 + 1) * 64 + l) * 4;
            for (int r = 0; r < 4; ++r) {
                ph[r] = hi[2 * r] | (hi[2 * r + 1] << 16);
                pl[r] = lo[2 * r] | (lo[2 * r + 1] << 16);
            }
        }
    }
}

__global__ void __launch_bounds__(64)
pinn_mfma_reg(const float* __restrict__ xs, const float* __restrict__ ys, const float* __restrict__ ts,
              const float* __restrict__ W_in, const float* __restrict__ b_in,
              const float* __restrict__ W_out, const float* __restrict__ b_out,
              const float* __restrict__ lam1p, const float* __restrict__ lam2p,
              const unsigned* __restrict__ wsu,
              float* __restrict__ out, int N)
{
    const int l  = threadIdx.x;
    const int g  = l >> 4, pt = l & 15;
    const int idx0 = blockIdx.x * PTS;
    const int pi = min(idx0 + pt, N - 1);

    // Layer-input B-fragments, register-resident. comps 9,10: hi-only (Lx/Ly tolerate bf16 X:
    // they never feed back into lower comps and reach outputs only via lam2=0.01 damping).
    u32x4 Bh[NC], Bl[NC];

    // ---- input layer ----
    const float xv = xs[pi], yv = ys[pi], tv = ts[pi];
    #pragma unroll
    for (int pr = 0; pr < 2; ++pr) {
        float nvA[NC], nvB[NC];
        input_neuron(4 * g + 2 * pr,     xv, yv, tv, W_in, b_in, nvA);
        input_neuron(4 * g + 2 * pr + 1, xv, yv, tv, W_in, b_in, nvB);
        #pragma unroll
        for (int c = 0; c < NC; ++c) {
            if (c < 9) {
                u32 th, tl;
                pack_pair(nvA[c], nvB[c], th, tl);
                Bh[c][pr] = th; Bl[c][pr] = tl;
            } else {
                Bh[c][pr] = cvt_pk_bf16(nvA[c], nvB[c]);
            }
        }
    }
    if (g == 0) {
        #pragma unroll
        for (int pr = 0; pr < 2; ++pr) {
            float nvA[NC], nvB[NC];
            input_neuron(16 + 2 * pr,     xv, yv, tv, W_in, b_in, nvA);
            input_neuron(16 + 2 * pr + 1, xv, yv, tv, W_in, b_in, nvB);
            #pragma unroll
            for (int c = 0; c < NC; ++c) {
                if (c < 9) {
                    u32 th, tl;
                    pack_pair(nvA[c], nvB[c], th, tl);
                    Bh[c][2 + pr] = th; Bl[c][2 + pr] = tl;
                } else {
                    Bh[c][2 + pr] = cvt_pk_bf16(nvA[c], nvB[c]);
                }
            }
        }
    } else {
        #pragma unroll
        for (int c = 0; c < NC; ++c) { Bh[c][2] = 0u; Bh[c][3] = 0u; Bl[c][2] = 0u; Bl[c][3] = 0u; }
    }
    // bias row k=20 (g==1, e=4): X=1.0 in comp 0 only
    Bh[0][2] = (g == 1) ? 0x3F80u : Bh[0][2];
    Bl[0][2] = (g == 1) ? 0u      : Bl[0][2];

    // ---- hidden layers 0..NLAY-2: MFMA + activation + repack ----
    const u32x4* wp = (const u32x4*)wsu;
    u32x4 f0 = wp[0 * 64 + l];
    u32x4 f1 = wp[1 * 64 + l];
    u32x4 f2 = wp[2 * 64 + l];
    u32x4 f3 = wp[3 * 64 + l];

    #pragma unroll 1
    for (int layer = 0; layer < NLAY - 1; ++layer) {
        const int nl = layer + 1;
        u32x4 n0 = wp[(nl * 4 + 0) * 64 + l];
        u32x4 n1 = wp[(nl * 4 + 1) * 64 + l];
        u32x4 n2 = wp[(nl * 4 + 2) * 64 + l];
        u32x4 n3 = wp[(nl * 4 + 3) * 64 + l];

        const bf16x8 ah0 = __builtin_bit_cast(bf16x8, f0);
        const bf16x8 al0 = __builtin_bit_cast(bf16x8, f1);
        const bf16x8 ah1 = __builtin_bit_cast(bf16x8, f2);
        const bf16x8 al1 = __builtin_bit_cast(bf16x8, f3);

        f32x4 acc1[NC], acc2[NC];
        #pragma unroll
        for (int c = 0; c < NC; ++c) {
            const bf16x8 bh = __builtin_bit_cast(bf16x8, Bh[c]);
            const f32x4 z = (f32x4){0.f, 0.f, 0.f, 0.f};
            f32x4 a1 = __builtin_amdgcn_mfma_f32_16x16x32_bf16(ah0, bh, z, 0, 0, 0);
            f32x4 a2 = __builtin_amdgcn_mfma_f32_16x16x32_bf16(ah1, bh, z, 0, 0, 0);
            if (c < 9) {
                const bf16x8 bl = __builtin_bit_cast(bf16x8, Bl[c]);
                a1 = __builtin_amdgcn_mfma_f32_16x16x32_bf16(ah0, bl, a1, 0, 0, 0);
                a2 = __builtin_amdgcn_mfma_f32_16x16x32_bf16(ah1, bl, a2, 0, 0, 0);
            }
            a1 = __builtin_amdgcn_mfma_f32_16x16x32_bf16(al0, bh, a1, 0, 0, 0);
            a2 = __builtin_amdgcn_mfma_f32_16x16x32_bf16(al1, bh, a2, 0, 0, 0);
            acc1[c] = a1;
            acc2[c] = a2;
        }

        // activation + repack (uniform across lanes: g>0 tile2 accs are exactly 0)
        #pragma unroll
        for (int pr = 0; pr < 2; ++pr) {
            float aA[NC], aB[NC], nvA[NC], nvB[NC];
            #pragma unroll
            for (int c = 0; c < NC; ++c) { aA[c] = acc1[c][2 * pr]; aB[c] = acc1[c][2 * pr + 1]; }
            jet_activate(aA, nvA);
            jet_activate(aB, nvB);
            #pragma unroll
            for (int c = 0; c < NC; ++c) {
                if (c < 9) {
                    u32 th, tl;
                    pack_pair(nvA[c], nvB[c], th, tl);
                    Bh[c][pr] = th; Bl[c][pr] = tl;
                } else {
                    Bh[c][pr] = cvt_pk_bf16(nvA[c], nvB[c]);
                }
            }
        }
        #pragma unroll
        for (int pr = 0; pr < 2; ++pr) {
            float aA[NC], aB[NC], nvA[NC], nvB[NC];
            #pragma unroll
            for (int c = 0; c < NC; ++c) { aA[c] = acc2[c][2 * pr]; aB[c] = acc2[c][2 * pr + 1]; }
            jet_activate(aA, nvA);
            jet_activate(aB, nvB);
            #pragma unroll
            for (int c = 0; c < NC; ++c) {
                if (c < 9) {
                    u32 th, tl;
                    pack_pair(nvA[c], nvB[c], th, tl);
                    Bh[c][2 + pr] = th; Bl[c][2 + pr] = tl;
                } else {
                    Bh[c][2 + pr] = cvt_pk_bf16(nvA[c], nvB[c]);
                }
            }
        }
        Bh[0][2] = (g == 1) ? 0x3F80u : Bh[0][2];
        Bl[0][2] = (g == 1) ? 0u      : Bl[0][2];

        f0 = n0; f1 = n1; f2 = n2; f3 = n3;
    }

    // ---- last hidden layer: MFMA + activation fused directly into output reduction ----
    float su = 0, sv = 0, sp = 0, spx = 0, spy = 0, svx = 0;
    float sux = 0, suy = 0, svt = 0, sut = 0, slx = 0, sly = 0;
    {
        const bf16x8 ah0 = __builtin_bit_cast(bf16x8, f0);
        const bf16x8 al0 = __builtin_bit_cast(bf16x8, f1);
        const bf16x8 ah1 = __builtin_bit_cast(bf16x8, f2);
        const bf16x8 al1 = __builtin_bit_cast(bf16x8, f3);

        f32x4 acc1[NC], acc2[NC];
        #pragma unroll
        for (int c = 0; c < NC; ++c) {
            const bf16x8 bh = __builtin_bit_cast(bf16x8, Bh[c]);
            const f32x4 z = (f32x4){0.f, 0.f, 0.f, 0.f};
            f32x4 a1 = __builtin_amdgcn_mfma_f32_16x16x32_bf16(ah0, bh, z, 0, 0, 0);
            f32x4 a2 = __builtin_amdgcn_mfma_f32_16x16x32_bf16(ah1, bh, z, 0, 0, 0);
            if (c < 9) {
                const bf16x8 bl = __builtin_bit_cast(bf16x8, Bl[c]);
                a1 = __builtin_amdgcn_mfma_f32_16x16x32_bf16(ah0, bl, a1, 0, 0, 0);
                a2 = __builtin_amdgcn_mfma_f32_16x16x32_bf16(ah1, bl, a2, 0, 0, 0);
            }
            a1 = __builtin_amdgcn_mfma_f32_16x16x32_bf16(al0, bh, a1, 0, 0, 0);
            a2 = __builtin_amdgcn_mfma_f32_16x16x32_bf16(al1, bh, a2, 0, 0, 0);
            acc1[c] = a1;
            acc2[c] = a2;
        }

        // tile1 slots: j = 4g+s, all real
        #pragma unroll
        for (int s = 0; s < 4; ++s) {
            float a[NC], nv[NC];
            #pragma unroll
            for (int c = 0; c < NC; ++c) a[c] = acc1[c][s];
            jet_activate(a, nv);
            const int j = 4 * g + s;
            const float w0 = W_out[2 * j], w1 = W_out[2 * j + 1];
            sp  = fmaf(w1, nv[0], sp);
            sv  = fmaf(w0, nv[1], sv);    spx = fmaf(w1, nv[1], spx);
            su  = fmaf(w0, nv[2], su);    spy = fmaf(w1, nv[2], spy);
            svx = fmaf(w0, nv[4], svx);
            sux = fmaf(w0, nv[5], sux);
            suy = fmaf(w0, nv[6], suy);
            svt = fmaf(w0, nv[7], svt);
            sut = fmaf(w0, nv[8], sut);
            slx = fmaf(w0, nv[9], slx);
            sly = fmaf(w0, nv[10], sly);
        }
        // tile2 slots: j2 = 16+4g+s, real only for j2 < 20 (g==0); others zero accs + masked w
        #pragma unroll
        for (int s = 0; s < 4; ++s) {
            float a[NC], nv[NC];
            #pragma unroll
            for (int c = 0; c < NC; ++c) a[c] = acc2[c][s];
            jet_activate(a, nv);
            const int j2 = 16 + 4 * g + s;
            const int jc = (j2 < HID) ? j2 : 0;
            const float valid = (j2 < HID) ? 1.0f : 0.0f;
            const float w0 = W_out[2 * jc] * valid, w1 = W_out[2 * jc + 1] * valid;
            sp  = fmaf(w1, nv[0], sp);
            sv  = fmaf(w0, nv[1], sv);    spx = fmaf(w1, nv[1], spx);
            su  = fmaf(w0, nv[2], su);    spy = fmaf(w1, nv[2], spy);
            svx = fmaf(w0, nv[4], svx);
            sux = fmaf(w0, nv[5], sux);
            suy = fmaf(w0, nv[6], suy);
            svt = fmaf(w0, nv[7], svt);
            sut = fmaf(w0, nv[8], sut);
            slx = fmaf(w0, nv[9], slx);
            sly = fmaf(w0, nv[10], sly);
        }
    }

    // reduce over the 4 lane-groups (lanes l, l^16, l^32, l^48 share pt)
    #define RED_(x) x += __shfl_xor(x, 16); x += __shfl_xor(x, 32)
    RED_(su); RED_(sv); RED_(sp); RED_(spx); RED_(spy); RED_(svx);
    RED_(sux); RED_(suy); RED_(svt); RED_(sut); RED_(slx); RED_(sly);
    #undef RED_

    if (g == 0 && idx0 + pt < N) {
        const float l1 = lam1p[0], l2 = lam2p[0];
        const float u = su, v = -sv, p = sp + b_out[1];
        const float fu = sut + l1 * (u * sux + v * suy) + spx - l2 * sly;
        const float fv = -svt + l1 * (u * (-svx) + v * (-sux)) + spy + l2 * slx;
        out[idx0 + pt]         = u;
        out[N + idx0 + pt]     = v;
        out[2 * N + idx0 + pt] = p;
        out[3 * N + idx0 + pt] = fu;
        out[4 * N + idx0 + pt] = fv;
    }
}

extern "C" void kernel_launch(void* const* d_in, const int* in_sizes, int n_in,
                              void* d_out, int out_size, void* d_ws, size_t ws_size,
                              hipStream_t stream) {
    const float* xs    = (const float*)d_in[0];
    const float* ys    = (const float*)d_in[1];
    const float* ts    = (const float*)d_in[2];
    const float* W_in  = (const float*)d_in[3];
    const float* b_in  = (const float*)d_in[4];
    const float* W_hid = (const float*)d_in[5];
    const float* b_hid = (const float*)d_in[6];
    const float* W_out = (const float*)d_in[7];
    const float* b_out = (const float*)d_in[8];
    const float* lam1  = (const float*)d_in[9];
    const float* lam2  = (const float*)d_in[10];
    float* out = (float*)d_out;

    const int N = in_sizes[0];
    wfrag_setup<<<1, 64, 0, stream>>>(W_hid, b_hid, (unsigned*)d_ws);
    const int grid = (N + PTS - 1) / PTS;
    pinn_mfma_reg<<<grid, 64, 0, stream>>>(xs, ys, ts, W_in, b_in, W_out, b_out,
                                           lam1, lam2, (const unsigned*)d_ws, out, N);
}

// Round 15
// 123.233 us; speedup vs baseline: 2.6447x; 1.0141x over previous
//
#include <hip/hip_runtime.h>

typedef float  f32x4  __attribute__((ext_vector_type(4)));
typedef short  bf16x8 __attribute__((ext_vector_type(8)));
typedef unsigned int u32;
typedef u32 u32x4 __attribute__((ext_vector_type(4)));

#define HID  20
#define NLAY 7
#define NC   11      // 0=val 1=gx 2=gy 3=gt 4=hxx 5=hxy 6=hyy 7=hxt 8=hyt 9=Lx 10=Ly
#define PTS  16      // points per wave

__device__ __forceinline__ float tanh_derivs(float a, float& d1, float& d2, float& d3) {
    const float e = __expf(2.0f * a);
    const float s = 1.0f - __fdividef(2.0f, e + 1.0f);
    d1 = 1.0f - s * s;
    d2 = -2.0f * s * d1;
    d3 = -2.0f * (d1 * d1 + s * d2);
    return s;
}

// jet chain rule through tanh: a[] = pre-activation jet, nv[] = post-activation jet
__device__ __forceinline__ void jet_activate(const float* a, float* nv) {
    float d1, d2, d3;
    const float s = tanh_derivs(a[0], d1, d2, d3);
    const float gx = a[1], gy = a[2], gt = a[3];
    const float hxx = a[4], hxy = a[5], hyy = a[6];
    const float hxt = a[7], hyt = a[8];
    const float g2 = gx * gx + gy * gy;
    nv[0] = s;
    nv[1] = d1 * gx;  nv[2] = d1 * gy;  nv[3] = d1 * gt;
    nv[4] = fmaf(d2, gx * gx, d1 * hxx);
    nv[5] = fmaf(d2, gx * gy, d1 * hxy);
    nv[6] = fmaf(d2, gy * gy, d1 * hyy);
    nv[7] = fmaf(d2, gx * gt, d1 * hxt);
    nv[8] = fmaf(d2, gy * gt, d1 * hyt);
    nv[9]  = d3 * gx * g2 + d2 * (3.f * gx * hxx + 2.f * gy * hxy + gx * hyy) + d1 * a[9];
    nv[10] = d3 * gy * g2 + d2 * (3.f * gy * hyy + 2.f * gx * hxy + gy * hxx) + d1 * a[10];
}

// packed bf16 convert: dst.lo16 = bf16(a), dst.hi16 = bf16(b)  (RNE)
__device__ __forceinline__ u32 cvt_pk_bf16(float a, float b) {
    u32 r;
    asm("v_cvt_pk_bf16_f32 %0, %1, %2" : "=v"(r) : "v"(a), "v"(b));
    return r;
}

// hi word + exact residual lo word
__device__ __forceinline__ void pack_pair(float v0, float v1, u32& wh, u32& wl) {
    wh = cvt_pk_bf16(v0, v1);
    const float h0 = __uint_as_float(wh << 16);
    const float h1 = __uint_as_float(wh & 0xFFFF0000u);
    wl = cvt_pk_bf16(v0 - h0, v1 - h1);
}

__device__ __forceinline__ void input_neuron(int j, float xv, float yv, float tv,
                                             const float* __restrict__ W_in,
                                             const float* __restrict__ b_in, float* nv) {
    const float w0 = W_in[j], w1 = W_in[HID + j], w2 = W_in[2 * HID + j];
    const float a0 = fmaf(xv, w0, fmaf(yv, w1, fmaf(tv, w2, b_in[j])));
    float d1, d2, d3;
    const float s = tanh_derivs(a0, d1, d2, d3);
    const float g2w = w0 * w0 + w1 * w1;
    nv[0] = s;        nv[1] = d1 * w0;  nv[2] = d1 * w1;  nv[3] = d1 * w2;
    nv[4] = d2 * w0 * w0; nv[5] = d2 * w0 * w1; nv[6] = d2 * w1 * w1;
    nv[7] = d2 * w0 * w2; nv[8] = d2 * w1 * w2;
    nv[9] = d3 * w0 * g2w; nv[10] = d3 * w1 * g2w;
}

// ---- setup: pack W_hid (+bias at k=20) into MFMA A-fragments (hi/lo bf16) in ws ----
// HW-verified (r11/r13/r14): lane l holds m=l&15, e<4: k=4*(l>>4)+e ; e>=4: k=16+4*(l>>4)+(e-4)
__global__ void wfrag_setup(const float* __restrict__ W_hid,
                            const float* __restrict__ b_hid,
                            unsigned* __restrict__ wsu)
{
    const int l = threadIdx.x;
    const int g = l >> 4, m = l & 15;
    for (int layer = 0; layer < NLAY; ++layer) {
        for (int jt = 0; jt < 2; ++jt) {
            const int j = jt * 16 + m;
            unsigned hi[8], lo[8];
            for (int e = 0; e < 8; ++e) {
                const int k = (e < 4) ? (4 * g + e) : (16 + 4 * g + (e - 4));
                float w = 0.0f;
                if (j < HID) {
                    if (k < HID)       w = W_hid[(layer * HID + k) * HID + j];
                    else if (k == HID) w = b_hid[layer * HID + j];
                }
                const unsigned hb = __float_as_uint(w) & 0xFFFF0000u;
                const float lf = w - __uint_as_float(hb);
                hi[e] = hb >> 16;
                lo[e] = __float_as_uint(lf) >> 16;
            }
            unsigned* ph = wsu + (((layer * 2 + jt) * 2 + 0) * 64 + l) * 4;
            unsigned* pl = wsu + (((layer * 2 + jt) * 2 + 1) * 64 + l) * 4;
            for (int r = 0; r < 4; ++r) {
                ph[r] = hi[2 * r] | (hi[2 * r + 1] << 16);
                pl[r] = lo[2 * r] | (lo[2 * r + 1] << 16);
            }
        }
    }
}

__global__ void __launch_bounds__(256)
pinn_mfma_reg(const float* __restrict__ xs, const float* __restrict__ ys, const float* __restrict__ ts,
              const float* __restrict__ W_in, const float* __restrict__ b_in,
              const float* __restrict__ W_out, const float* __restrict__ b_out,
              const float* __restrict__ lam1p, const float* __restrict__ lam2p,
              const unsigned* __restrict__ wsu,
              float* __restrict__ out, int N)
{
    const int l  = threadIdx.x & 63;        // lane within wave
    const int wid = threadIdx.x >> 6;       // wave within block (0..3)
    const int g  = l >> 4, pt = l & 15;
    const int idx0 = blockIdx.x * (4 * PTS) + wid * PTS;
    const int pi = min(idx0 + pt, N - 1);

    // Layer-input B-fragments, register-resident. comps 9,10: hi-only (Lx/Ly tolerate bf16 X:
    // they never feed back into lower comps and reach outputs only via lam2=0.01 damping).
    u32x4 Bh[NC], Bl[NC];

    // ---- input layer ----
    const float xv = xs[pi], yv = ys[pi], tv = ts[pi];
    #pragma unroll
    for (int pr = 0; pr < 2; ++pr) {
        float nvA[NC], nvB[NC];
        input_neuron(4 * g + 2 * pr,     xv, yv, tv, W_in, b_in, nvA);
        input_neuron(4 * g + 2 * pr + 1, xv, yv, tv, W_in, b_in, nvB);
        #pragma unroll
        for (int c = 0; c < NC; ++c) {
            if (c < 9) {
                u32 th, tl;
                pack_pair(nvA[c], nvB[c], th, tl);
                Bh[c][pr] = th; Bl[c][pr] = tl;
            } else {
                Bh[c][pr] = cvt_pk_bf16(nvA[c], nvB[c]);
            }
        }
    }
    if (g == 0) {
        #pragma unroll
        for (int pr = 0; pr < 2; ++pr) {
            float nvA[NC], nvB[NC];
            input_neuron(16 + 2 * pr,     xv, yv, tv, W_in, b_in, nvA);
            input_neuron(16 + 2 * pr + 1, xv, yv, tv, W_in, b_in, nvB);
            #pragma unroll
            for (int c = 0; c < NC; ++c) {
                if (c < 9) {
                    u32 th, tl;
                    pack_pair(nvA[c], nvB[c], th, tl);
                    Bh[c][2 + pr] = th; Bl[c][2 + pr] = tl;
                } else {
                    Bh[c][2 + pr] = cvt_pk_bf16(nvA[c], nvB[c]);
                }
            }
        }
    } else {
        #pragma unroll
        for (int c = 0; c < NC; ++c) { Bh[c][2] = 0u; Bh[c][3] = 0u; Bl[c][2] = 0u; Bl[c][3] = 0u; }
    }
    // bias row k=20 (g==1, e=4): X=1.0 in comp 0 only
    Bh[0][2] = (g == 1) ? 0x3F80u : Bh[0][2];
    Bl[0][2] = (g == 1) ? 0u      : Bl[0][2];

    // ---- hidden layers 0..NLAY-2: MFMA + activation + repack ----
    const u32x4* wp = (const u32x4*)wsu;
    u32x4 f0 = wp[0 * 64 + l];
    u32x4 f1 = wp[1 * 64 + l];
    u32x4 f2 = wp[2 * 64 + l];
    u32x4 f3 = wp[3 * 64 + l];

    #pragma unroll 1
    for (int layer = 0; layer < NLAY - 1; ++layer) {
        const int nl = layer + 1;
        u32x4 n0 = wp[(nl * 4 + 0) * 64 + l];
        u32x4 n1 = wp[(nl * 4 + 1) * 64 + l];
        u32x4 n2 = wp[(nl * 4 + 2) * 64 + l];
        u32x4 n3 = wp[(nl * 4 + 3) * 64 + l];

        const bf16x8 ah0 = __builtin_bit_cast(bf16x8, f0);
        const bf16x8 al0 = __builtin_bit_cast(bf16x8, f1);
        const bf16x8 ah1 = __builtin_bit_cast(bf16x8, f2);
        const bf16x8 al1 = __builtin_bit_cast(bf16x8, f3);

        f32x4 acc1[NC], acc2[NC];
        #pragma unroll
        for (int c = 0; c < NC; ++c) {
            const bf16x8 bh = __builtin_bit_cast(bf16x8, Bh[c]);
            const f32x4 z = (f32x4){0.f, 0.f, 0.f, 0.f};
            f32x4 a1 = __builtin_amdgcn_mfma_f32_16x16x32_bf16(ah0, bh, z, 0, 0, 0);
            f32x4 a2 = __builtin_amdgcn_mfma_f32_16x16x32_bf16(ah1, bh, z, 0, 0, 0);
            if (c < 9) {
                const bf16x8 bl = __builtin_bit_cast(bf16x8, Bl[c]);
                a1 = __builtin_amdgcn_mfma_f32_16x16x32_bf16(ah0, bl, a1, 0, 0, 0);
                a2 = __builtin_amdgcn_mfma_f32_16x16x32_bf16(ah1, bl, a2, 0, 0, 0);
            }
            a1 = __builtin_amdgcn_mfma_f32_16x16x32_bf16(al0, bh, a1, 0, 0, 0);
            a2 = __builtin_amdgcn_mfma_f32_16x16x32_bf16(al1, bh, a2, 0, 0, 0);
            acc1[c] = a1;
            acc2[c] = a2;
        }

        // activation + repack (uniform across lanes: g>0 tile2 accs are exactly 0)
        #pragma unroll
        for (int pr = 0; pr < 2; ++pr) {
            float aA[NC], aB[NC], nvA[NC], nvB[NC];
            #pragma unroll
            for (int c = 0; c < NC; ++c) { aA[c] = acc1[c][2 * pr]; aB[c] = acc1[c][2 * pr + 1]; }
            jet_activate(aA, nvA);
            jet_activate(aB, nvB);
            #pragma unroll
            for (int c = 0; c < NC; ++c) {
                if (c < 9) {
                    u32 th, tl;
                    pack_pair(nvA[c], nvB[c], th, tl);
                    Bh[c][pr] = th; Bl[c][pr] = tl;
                } else {
                    Bh[c][pr] = cvt_pk_bf16(nvA[c], nvB[c]);
                }
            }
        }
        #pragma unroll
        for (int pr = 0; pr < 2; ++pr) {
            float aA[NC], aB[NC], nvA[NC], nvB[NC];
            #pragma unroll
            for (int c = 0; c < NC; ++c) { aA[c] = acc2[c][2 * pr]; aB[c] = acc2[c][2 * pr + 1]; }
            jet_activate(aA, nvA);
            jet_activate(aB, nvB);
            #pragma unroll
            for (int c = 0; c < NC; ++c) {
                if (c < 9) {
                    u32 th, tl;
                    pack_pair(nvA[c], nvB[c], th, tl);
                    Bh[c][2 + pr] = th; Bl[c][2 + pr] = tl;
                } else {
                    Bh[c][2 + pr] = cvt_pk_bf16(nvA[c], nvB[c]);
                }
            }
        }
        Bh[0][2] = (g == 1) ? 0x3F80u : Bh[0][2];
        Bl[0][2] = (g == 1) ? 0u      : Bl[0][2];

        f0 = n0; f1 = n1; f2 = n2; f3 = n3;
    }

    // ---- last hidden layer: MFMA + activation fused directly into output reduction ----
    float su = 0, sv = 0, sp = 0, spx = 0, spy = 0, svx = 0;
    float sux = 0, suy = 0, svt = 0, sut = 0, slx = 0, sly = 0;
    {
        const bf16x8 ah0 = __builtin_bit_cast(bf16x8, f0);
        const bf16x8 al0 = __builtin_bit_cast(bf16x8, f1);
        const bf16x8 ah1 = __builtin_bit_cast(bf16x8, f2);
        const bf16x8 al1 = __builtin_bit_cast(bf16x8, f3);

        f32x4 acc1[NC], acc2[NC];
        #pragma unroll
        for (int c = 0; c < NC; ++c) {
            const bf16x8 bh = __builtin_bit_cast(bf16x8, Bh[c]);
            const f32x4 z = (f32x4){0.f, 0.f, 0.f, 0.f};
            f32x4 a1 = __builtin_amdgcn_mfma_f32_16x16x32_bf16(ah0, bh, z, 0, 0, 0);
            f32x4 a2 = __builtin_amdgcn_mfma_f32_16x16x32_bf16(ah1, bh, z, 0, 0, 0);
            if (c < 9) {
                const bf16x8 bl = __builtin_bit_cast(bf16x8, Bl[c]);
                a1 = __builtin_amdgcn_mfma_f32_16x16x32_bf16(ah0, bl, a1, 0, 0, 0);
                a2 = __builtin_amdgcn_mfma_f32_16x16x32_bf16(ah1, bl, a2, 0, 0, 0);
            }
            a1 = __builtin_amdgcn_mfma_f32_16x16x32_bf16(al0, bh, a1, 0, 0, 0);
            a2 = __builtin_amdgcn_mfma_f32_16x16x32_bf16(al1, bh, a2, 0, 0, 0);
            acc1[c] = a1;
            acc2[c] = a2;
        }

        // tile1 slots: j = 4g+s, all real
        #pragma unroll
        for (int s = 0; s < 4; ++s) {
            float a[NC], nv[NC];
            #pragma unroll
            for (int c = 0; c < NC; ++c) a[c] = acc1[c][s];
            jet_activate(a, nv);
            const int j = 4 * g + s;
            const float w0 = W_out[2 * j], w1 = W_out[2 * j + 1];
            sp  = fmaf(w1, nv[0], sp);
            sv  = fmaf(w0, nv[1], sv);    spx = fmaf(w1, nv[1], spx);
            su  = fmaf(w0, nv[2], su);    spy = fmaf(w1, nv[2], spy);
            svx = fmaf(w0, nv[4], svx);
            sux = fmaf(w0, nv[5], sux);
            suy = fmaf(w0, nv[6], suy);
            svt = fmaf(w0, nv[7], svt);
            sut = fmaf(w0, nv[8], sut);
            slx = fmaf(w0, nv[9], slx);
            sly = fmaf(w0, nv[10], sly);
        }
        // tile2 slots: j2 = 16+4g+s, real only for j2 < 20 (g==0); others zero accs + masked w
        #pragma unroll
        for (int s = 0; s < 4; ++s) {
            float a[NC], nv[NC];
            #pragma unroll
            for (int c = 0; c < NC; ++c) a[c] = acc2[c][s];
            jet_activate(a, nv);
            const int j2 = 16 + 4 * g + s;
            const int jc = (j2 < HID) ? j2 : 0;
            const float valid = (j2 < HID) ? 1.0f : 0.0f;
            const float w0 = W_out[2 * jc] * valid, w1 = W_out[2 * jc + 1] * valid;
            sp  = fmaf(w1, nv[0], sp);
            sv  = fmaf(w0, nv[1], sv);    spx = fmaf(w1, nv[1], spx);
            su  = fmaf(w0, nv[2], su);    spy = fmaf(w1, nv[2], spy);
            svx = fmaf(w0, nv[4], svx);
            sux = fmaf(w0, nv[5], sux);
            suy = fmaf(w0, nv[6], suy);
            svt = fmaf(w0, nv[7], svt);
            sut = fmaf(w0, nv[8], sut);
            slx = fmaf(w0, nv[9], slx);
            sly = fmaf(w0, nv[10], sly);
        }
    }

    // reduce over the 4 lane-groups (lanes l, l^16, l^32, l^48 share pt)
    #define RED_(x) x += __shfl_xor(x, 16); x += __shfl_xor(x, 32)
    RED_(su); RED_(sv); RED_(sp); RED_(spx); RED_(spy); RED_(svx);
    RED_(sux); RED_(suy); RED_(svt); RED_(sut); RED_(slx); RED_(sly);
    #undef RED_

    if (g == 0 && idx0 + pt < N) {
        const float l1 = lam1p[0], l2 = lam2p[0];
        const float u = su, v = -sv, p = sp + b_out[1];
        const float fu = sut + l1 * (u * sux + v * suy) + spx - l2 * sly;
        const float fv = -svt + l1 * (u * (-svx) + v * (-sux)) + spy + l2 * slx;
        out[idx0 + pt]         = u;
        out[N + idx0 + pt]     = v;
        out[2 * N + idx0 + pt] = p;
        out[3 * N + idx0 + pt] = fu;
        out[4 * N + idx0 + pt] = fv;
    }
}

extern "C" void kernel_launch(void* const* d_in, const int* in_sizes, int n_in,
                              void* d_out, int out_size, void* d_ws, size_t ws_size,
                              hipStream_t stream) {
    const float* xs    = (const float*)d_in[0];
    const float* ys    = (const float*)d_in[1];
    const float* ts    = (const float*)d_in[2];
    const float* W_in  = (const float*)d_in[3];
    const float* b_in  = (const float*)d_in[4];
    const float* W_hid = (const float*)d_in[5];
    const float* b_hid = (const float*)d_in[6];
    const float* W_out = (const float*)d_in[7];
    const float* b_out = (const float*)d_in[8];
    const float* lam1  = (const float*)d_in[9];
    const float* lam2  = (const float*)d_in[10];
    float* out = (float*)d_out;

    const int N = in_sizes[0];
    wfrag_setup<<<1, 64, 0, stream>>>(W_hid, b_hid, (unsigned*)d_ws);
    const int grid = (N + 4 * PTS - 1) / (4 * PTS);
    pinn_mfma_reg<<<grid, 256, 0, stream>>>(xs, ys, ts, W_in, b_in, W_out, b_out,
                                            lam1, lam2, (const unsigned*)d_ws, out, N);
}

// Round 16
// 111.189 us; speedup vs baseline: 2.9311x; 1.1083x over previous
//
#include <hip/hip_runtime.h>

typedef float  f32x4  __attribute__((ext_vector_type(4)));
typedef short  bf16x8 __attribute__((ext_vector_type(8)));
typedef unsigned int u32;
typedef u32 u32x4 __attribute__((ext_vector_type(4)));

#define HID  20
#define NLAY 7
#define NC   11      // 0=val 1=gx 2=gy 3=gt 4=hxx 5=hxy 6=hyy 7=hxt 8=hyt 9=Lx 10=Ly
#define NLO  4       // comps with hi+lo X representation (nonlinearly amplified ones)
#define PTS  16      // points per wave

__device__ __forceinline__ float tanh_derivs(float a, float& d1, float& d2, float& d3) {
    const float e = __expf(2.0f * a);
    const float s = 1.0f - __fdividef(2.0f, e + 1.0f);
    d1 = 1.0f - s * s;
    d2 = -2.0f * s * d1;
    d3 = -2.0f * (d1 * d1 + s * d2);
    return s;
}

// jet chain rule through tanh: a[] = pre-activation jet, nv[] = post-activation jet
__device__ __forceinline__ void jet_activate(const float* a, float* nv) {
    float d1, d2, d3;
    const float s = tanh_derivs(a[0], d1, d2, d3);
    const float gx = a[1], gy = a[2], gt = a[3];
    const float hxx = a[4], hxy = a[5], hyy = a[6];
    const float hxt = a[7], hyt = a[8];
    const float g2 = gx * gx + gy * gy;
    nv[0] = s;
    nv[1] = d1 * gx;  nv[2] = d1 * gy;  nv[3] = d1 * gt;
    nv[4] = fmaf(d2, gx * gx, d1 * hxx);
    nv[5] = fmaf(d2, gx * gy, d1 * hxy);
    nv[6] = fmaf(d2, gy * gy, d1 * hyy);
    nv[7] = fmaf(d2, gx * gt, d1 * hxt);
    nv[8] = fmaf(d2, gy * gt, d1 * hyt);
    nv[9]  = d3 * gx * g2 + d2 * (3.f * gx * hxx + 2.f * gy * hxy + gx * hyy) + d1 * a[9];
    nv[10] = d3 * gy * g2 + d2 * (3.f * gy * hyy + 2.f * gx * hxy + gy * hxx) + d1 * a[10];
}

// packed bf16 convert: dst.lo16 = bf16(a), dst.hi16 = bf16(b)  (RNE)
__device__ __forceinline__ u32 cvt_pk_bf16(float a, float b) {
    u32 r;
    asm("v_cvt_pk_bf16_f32 %0, %1, %2" : "=v"(r) : "v"(a), "v"(b));
    return r;
}

// hi word + exact residual lo word
__device__ __forceinline__ void pack_pair(float v0, float v1, u32& wh, u32& wl) {
    wh = cvt_pk_bf16(v0, v1);
    const float h0 = __uint_as_float(wh << 16);
    const float h1 = __uint_as_float(wh & 0xFFFF0000u);
    wl = cvt_pk_bf16(v0 - h0, v1 - h1);
}

__device__ __forceinline__ void input_neuron(int j, float xv, float yv, float tv,
                                             const float* __restrict__ W_in,
                                             const float* __restrict__ b_in, float* nv) {
    const float w0 = W_in[j], w1 = W_in[HID + j], w2 = W_in[2 * HID + j];
    const float a0 = fmaf(xv, w0, fmaf(yv, w1, fmaf(tv, w2, b_in[j])));
    float d1, d2, d3;
    const float s = tanh_derivs(a0, d1, d2, d3);
    const float g2w = w0 * w0 + w1 * w1;
    nv[0] = s;        nv[1] = d1 * w0;  nv[2] = d1 * w1;  nv[3] = d1 * w2;
    nv[4] = d2 * w0 * w0; nv[5] = d2 * w0 * w1; nv[6] = d2 * w1 * w1;
    nv[7] = d2 * w0 * w2; nv[8] = d2 * w1 * w2;
    nv[9] = d3 * w0 * g2w; nv[10] = d3 * w1 * g2w;
}

// ---- setup: pack W_hid (+bias at k=20) into MFMA A-fragments (hi/lo bf16) in ws ----
// HW-verified (r11/r13/r14): lane l holds m=l&15, e<4: k=4*(l>>4)+e ; e>=4: k=16+4*(l>>4)+(e-4)
__global__ void wfrag_setup(const float* __restrict__ W_hid,
                            const float* __restrict__ b_hid,
                            unsigned* __restrict__ wsu)
{
    const int l = threadIdx.x;
    const int g = l >> 4, m = l & 15;
    for (int layer = 0; layer < NLAY; ++layer) {
        for (int jt = 0; jt < 2; ++jt) {
            const int j = jt * 16 + m;
            unsigned hi[8], lo[8];
            for (int e = 0; e < 8; ++e) {
                const int k = (e < 4) ? (4 * g + e) : (16 + 4 * g + (e - 4));
                float w = 0.0f;
                if (j < HID) {
                    if (k < HID)       w = W_hid[(layer * HID + k) * HID + j];
                    else if (k == HID) w = b_hid[layer * HID + j];
                }
                const unsigned hb = __float_as_uint(w) & 0xFFFF0000u;
                const float lf = w - __uint_as_float(hb);
                hi[e] = hb >> 16;
                lo[e] = __float_as_uint(lf) >> 16;
            }
            unsigned* ph = wsu + (((layer * 2 + jt) * 2 + 0) * 64 + l) * 4;
            unsigned* pl = wsu + (((layer * 2 + jt) * 2 + 1) * 64 + l) * 4;
            for (int r = 0; r < 4; ++r) {
                ph[r] = hi[2 * r] | (hi[2 * r + 1] << 16);
                pl[r] = lo[2 * r] | (lo[2 * r + 1] << 16);
            }
        }
    }
}

__global__ void __launch_bounds__(256)
pinn_mfma_reg(const float* __restrict__ xs, const float* __restrict__ ys, const float* __restrict__ ts,
              const float* __restrict__ W_in, const float* __restrict__ b_in,
              const float* __restrict__ W_out, const float* __restrict__ b_out,
              const float* __restrict__ lam1p, const float* __restrict__ lam2p,
              const unsigned* __restrict__ wsu,
              float* __restrict__ out, int N)
{
    const int l  = threadIdx.x & 63;        // lane within wave
    const int wid = threadIdx.x >> 6;       // wave within block (0..3)
    const int g  = l >> 4, pt = l & 15;
    const int idx0 = blockIdx.x * (4 * PTS) + wid * PTS;
    const int pi = min(idx0 + pt, N - 1);

    // Layer-input B-fragments, register-resident.
    // comps 0..3 (val,gx,gy,gt): hi+lo (exact) — these feed the jet nonlinearly.
    // comps 4..10: hi-only bf16 — they propagate linearly (d1-contraction per layer)
    // and reach outputs with O(1) or lam2=0.01 weight; rounding fits the error budget.
    u32x4 Bh[NC], Bl[NLO];

    // ---- input layer ----
    const float xv = xs[pi], yv = ys[pi], tv = ts[pi];
    #pragma unroll
    for (int pr = 0; pr < 2; ++pr) {
        float nvA[NC], nvB[NC];
        input_neuron(4 * g + 2 * pr,     xv, yv, tv, W_in, b_in, nvA);
        input_neuron(4 * g + 2 * pr + 1, xv, yv, tv, W_in, b_in, nvB);
        #pragma unroll
        for (int c = 0; c < NC; ++c) {
            if (c < NLO) {
                u32 th, tl;
                pack_pair(nvA[c], nvB[c], th, tl);
                Bh[c][pr] = th; Bl[c][pr] = tl;
            } else {
                Bh[c][pr] = cvt_pk_bf16(nvA[c], nvB[c]);
            }
        }
    }
    if (g == 0) {
        #pragma unroll
        for (int pr = 0; pr < 2; ++pr) {
            float nvA[NC], nvB[NC];
            input_neuron(16 + 2 * pr,     xv, yv, tv, W_in, b_in, nvA);
            input_neuron(16 + 2 * pr + 1, xv, yv, tv, W_in, b_in, nvB);
            #pragma unroll
            for (int c = 0; c < NC; ++c) {
                if (c < NLO) {
                    u32 th, tl;
                    pack_pair(nvA[c], nvB[c], th, tl);
                    Bh[c][2 + pr] = th; Bl[c][2 + pr] = tl;
                } else {
                    Bh[c][2 + pr] = cvt_pk_bf16(nvA[c], nvB[c]);
                }
            }
        }
    } else {
        #pragma unroll
        for (int c = 0; c < NC; ++c) { Bh[c][2] = 0u; Bh[c][3] = 0u; }
        #pragma unroll
        for (int c = 0; c < NLO; ++c) { Bl[c][2] = 0u; Bl[c][3] = 0u; }
    }
    // bias row k=20 (g==1, e=4): X=1.0 in comp 0 only
    Bh[0][2] = (g == 1) ? 0x3F80u : Bh[0][2];
    Bl[0][2] = (g == 1) ? 0u      : Bl[0][2];

    // ---- hidden layers 0..NLAY-2: MFMA + activation + repack ----
    const u32x4* wp = (const u32x4*)wsu;
    u32x4 f0 = wp[0 * 64 + l];
    u32x4 f1 = wp[1 * 64 + l];
    u32x4 f2 = wp[2 * 64 + l];
    u32x4 f3 = wp[3 * 64 + l];

    #pragma unroll 1
    for (int layer = 0; layer < NLAY - 1; ++layer) {
        const int nl = layer + 1;
        u32x4 n0 = wp[(nl * 4 + 0) * 64 + l];
        u32x4 n1 = wp[(nl * 4 + 1) * 64 + l];
        u32x4 n2 = wp[(nl * 4 + 2) * 64 + l];
        u32x4 n3 = wp[(nl * 4 + 3) * 64 + l];

        const bf16x8 ah0 = __builtin_bit_cast(bf16x8, f0);
        const bf16x8 al0 = __builtin_bit_cast(bf16x8, f1);
        const bf16x8 ah1 = __builtin_bit_cast(bf16x8, f2);
        const bf16x8 al1 = __builtin_bit_cast(bf16x8, f3);

        f32x4 acc1[NC], acc2[NC];
        #pragma unroll
        for (int c = 0; c < NC; ++c) {
            const bf16x8 bh = __builtin_bit_cast(bf16x8, Bh[c]);
            const f32x4 z = (f32x4){0.f, 0.f, 0.f, 0.f};
            f32x4 a1 = __builtin_amdgcn_mfma_f32_16x16x32_bf16(ah0, bh, z, 0, 0, 0);
            f32x4 a2 = __builtin_amdgcn_mfma_f32_16x16x32_bf16(ah1, bh, z, 0, 0, 0);
            if (c < NLO) {
                const bf16x8 bl = __builtin_bit_cast(bf16x8, Bl[c]);
                a1 = __builtin_amdgcn_mfma_f32_16x16x32_bf16(ah0, bl, a1, 0, 0, 0);
                a2 = __builtin_amdgcn_mfma_f32_16x16x32_bf16(ah1, bl, a2, 0, 0, 0);
            }
            a1 = __builtin_amdgcn_mfma_f32_16x16x32_bf16(al0, bh, a1, 0, 0, 0);
            a2 = __builtin_amdgcn_mfma_f32_16x16x32_bf16(al1, bh, a2, 0, 0, 0);
            acc1[c] = a1;
            acc2[c] = a2;
        }

        // activation + repack (uniform across lanes: g>0 tile2 accs are exactly 0)
        #pragma unroll
        for (int pr = 0; pr < 2; ++pr) {
            float aA[NC], aB[NC], nvA[NC], nvB[NC];
            #pragma unroll
            for (int c = 0; c < NC; ++c) { aA[c] = acc1[c][2 * pr]; aB[c] = acc1[c][2 * pr + 1]; }
            jet_activate(aA, nvA);
            jet_activate(aB, nvB);
            #pragma unroll
            for (int c = 0; c < NC; ++c) {
                if (c < NLO) {
                    u32 th, tl;
                    pack_pair(nvA[c], nvB[c], th, tl);
                    Bh[c][pr] = th; Bl[c][pr] = tl;
                } else {
                    Bh[c][pr] = cvt_pk_bf16(nvA[c], nvB[c]);
                }
            }
        }
        #pragma unroll
        for (int pr = 0; pr < 2; ++pr) {
            float aA[NC], aB[NC], nvA[NC], nvB[NC];
            #pragma unroll
            for (int c = 0; c < NC; ++c) { aA[c] = acc2[c][2 * pr]; aB[c] = acc2[c][2 * pr + 1]; }
            jet_activate(aA, nvA);
            jet_activate(aB, nvB);
            #pragma unroll
            for (int c = 0; c < NC; ++c) {
                if (c < NLO) {
                    u32 th, tl;
                    pack_pair(nvA[c], nvB[c], th, tl);
                    Bh[c][2 + pr] = th; Bl[c][2 + pr] = tl;
                } else {
                    Bh[c][2 + pr] = cvt_pk_bf16(nvA[c], nvB[c]);
                }
            }
        }
        Bh[0][2] = (g == 1) ? 0x3F80u : Bh[0][2];
        Bl[0][2] = (g == 1) ? 0u      : Bl[0][2];

        f0 = n0; f1 = n1; f2 = n2; f3 = n3;
    }

    // ---- last hidden layer: MFMA + activation fused directly into output reduction ----
    float su = 0, sv = 0, sp = 0, spx = 0, spy = 0, svx = 0;
    float sux = 0, suy = 0, svt = 0, sut = 0, slx = 0, sly = 0;
    {
        const bf16x8 ah0 = __builtin_bit_cast(bf16x8, f0);
        const bf16x8 al0 = __builtin_bit_cast(bf16x8, f1);
        const bf16x8 ah1 = __builtin_bit_cast(bf16x8, f2);
        const bf16x8 al1 = __builtin_bit_cast(bf16x8, f3);

        f32x4 acc1[NC], acc2[NC];
        #pragma unroll
        for (int c = 0; c < NC; ++c) {
            const bf16x8 bh = __builtin_bit_cast(bf16x8, Bh[c]);
            const f32x4 z = (f32x4){0.f, 0.f, 0.f, 0.f};
            f32x4 a1 = __builtin_amdgcn_mfma_f32_16x16x32_bf16(ah0, bh, z, 0, 0, 0);
            f32x4 a2 = __builtin_amdgcn_mfma_f32_16x16x32_bf16(ah1, bh, z, 0, 0, 0);
            if (c < NLO) {
                const bf16x8 bl = __builtin_bit_cast(bf16x8, Bl[c]);
                a1 = __builtin_amdgcn_mfma_f32_16x16x32_bf16(ah0, bl, a1, 0, 0, 0);
                a2 = __builtin_amdgcn_mfma_f32_16x16x32_bf16(ah1, bl, a2, 0, 0, 0);
            }
            a1 = __builtin_amdgcn_mfma_f32_16x16x32_bf16(al0, bh, a1, 0, 0, 0);
            a2 = __builtin_amdgcn_mfma_f32_16x16x32_bf16(al1, bh, a2, 0, 0, 0);
            acc1[c] = a1;
            acc2[c] = a2;
        }

        // tile1 slots: j = 4g+s, all real
        #pragma unroll
        for (int s = 0; s < 4; ++s) {
            float a[NC], nv[NC];
            #pragma unroll
            for (int c = 0; c < NC; ++c) a[c] = acc1[c][s];
            jet_activate(a, nv);
            const int j = 4 * g + s;
            const float w0 = W_out[2 * j], w1 = W_out[2 * j + 1];
            sp  = fmaf(w1, nv[0], sp);
            sv  = fmaf(w0, nv[1], sv);    spx = fmaf(w1, nv[1], spx);
            su  = fmaf(w0, nv[2], su);    spy = fmaf(w1, nv[2], spy);
            svx = fmaf(w0, nv[4], svx);
            sux = fmaf(w0, nv[5], sux);
            suy = fmaf(w0, nv[6], suy);
            svt = fmaf(w0, nv[7], svt);
            sut = fmaf(w0, nv[8], sut);
            slx = fmaf(w0, nv[9], slx);
            sly = fmaf(w0, nv[10], sly);
        }
        // tile2 slots: j2 = 16+4g+s, real only for j2 < 20 (g==0); others zero accs + masked w
        #pragma unroll
        for (int s = 0; s < 4; ++s) {
            float a[NC], nv[NC];
            #pragma unroll
            for (int c = 0; c < NC; ++c) a[c] = acc2[c][s];
            jet_activate(a, nv);
            const int j2 = 16 + 4 * g + s;
            const int jc = (j2 < HID) ? j2 : 0;
            const float valid = (j2 < HID) ? 1.0f : 0.0f;
            const float w0 = W_out[2 * jc] * valid, w1 = W_out[2 * jc + 1] * valid;
            sp  = fmaf(w1, nv[0], sp);
            sv  = fmaf(w0, nv[1], sv);    spx = fmaf(w1, nv[1], spx);
            su  = fmaf(w0, nv[2], su);    spy = fmaf(w1, nv[2], spy);
            svx = fmaf(w0, nv[4], svx);
            sux = fmaf(w0, nv[5], sux);
            suy = fmaf(w0, nv[6], suy);
            svt = fmaf(w0, nv[7], svt);
            sut = fmaf(w0, nv[8], sut);
            slx = fmaf(w0, nv[9], slx);
            sly = fmaf(w0, nv[10], sly);
        }
    }

    // reduce over the 4 lane-groups (lanes l, l^16, l^32, l^48 share pt)
    #define RED_(x) x += __shfl_xor(x, 16); x += __shfl_xor(x, 32)
    RED_(su); RED_(sv); RED_(sp); RED_(spx); RED_(spy); RED_(svx);
    RED_(sux); RED_(suy); RED_(svt); RED_(sut); RED_(slx); RED_(sly);
    #undef RED_

    if (g == 0 && idx0 + pt < N) {
        const float l1 = lam1p[0], l2 = lam2p[0];
        const float u = su, v = -sv, p = sp + b_out[1];
        const float fu = sut + l1 * (u * sux + v * suy) + spx - l2 * sly;
        const float fv = -svt + l1 * (u * (-svx) + v * (-sux)) + spy + l2 * slx;
        out[idx0 + pt]         = u;
        out[N + idx0 + pt]     = v;
        out[2 * N + idx0 + pt] = p;
        out[3 * N + idx0 + pt] = fu;
        out[4 * N + idx0 + pt] = fv;
    }
}

extern "C" void kernel_launch(void* const* d_in, const int* in_sizes, int n_in,
                              void* d_out, int out_size, void* d_ws, size_t ws_size,
                              hipStream_t stream) {
    const float* xs    = (const float*)d_in[0];
    const float* ys    = (const float*)d_in[1];
    const float* ts    = (const float*)d_in[2];
    const float* W_in  = (const float*)d_in[3];
    const float* b_in  = (const float*)d_in[4];
    const float* W_hid = (const float*)d_in[5];
    const float* b_hid = (const float*)d_in[6];
    const float* W_out = (const float*)d_in[7];
    const float* b_out = (const float*)d_in[8];
    const float* lam1  = (const float*)d_in[9];
    const float* lam2  = (const float*)d_in[10];
    float* out = (float*)d_out;

    const int N = in_sizes[0];
    wfrag_setup<<<1, 64, 0, stream>>>(W_hid, b_hid, (unsigned*)d_ws);
    const int grid = (N + 4 * PTS - 1) / (4 * PTS);
    pinn_mfma_reg<<<grid, 256, 0, stream>>>(xs, ys, ts, W_in, b_in, W_out, b_out,
                                            lam1, lam2, (const unsigned*)d_ws, out, N);
}